// Round 4
// baseline (449.413 us; speedup 1.0000x reference)
//
#include <hip/hip_runtime.h>
#include <stdint.h>

#define NUM_HEADS 16
#define HEAD_DIM 64
#define D_MODEL 1024
#define SEQ 2048
#define BATCH 2

typedef unsigned short u16;
typedef __bf16 bf16x8 __attribute__((ext_vector_type(8)));
typedef float f32x4 __attribute__((ext_vector_type(4)));

__device__ __forceinline__ u16 f2bf(float f) {
    union { float f; uint32_t u; } v; v.f = f;
    uint32_t u = v.u;
    u += 0x7FFFu + ((u >> 16) & 1u);   // RNE
    return (u16)(u >> 16);
}
__device__ __forceinline__ float bf2f(u16 h) {
    union { uint32_t u; float f; } v; v.u = (uint32_t)h << 16; return v.f;
}

__device__ __forceinline__ bf16x8 ld8(const u16* p) {
    return *reinterpret_cast<const bf16x8*>(p);
}

__device__ __forceinline__ void gl_lds16(const void* g, void* l) {
    __builtin_amdgcn_global_load_lds(
        (const __attribute__((address_space(1))) void*)g,
        (__attribute__((address_space(3))) void*)l,
        16, 0, 0);
}

// ---- DPP 16-lane reductions (VALU pipe, not LDS pipe) ----
template <int CTRL>
__device__ __forceinline__ float dpp_mov(float x) {
    return __builtin_bit_cast(float,
        __builtin_amdgcn_update_dpp(0, __builtin_bit_cast(int, x), CTRL, 0xf, 0xf, true));
}
__device__ __forceinline__ float rowmax16(float x) {  // max over 16-lane row
    x = fmaxf(x, dpp_mov<0x121>(x));   // row_ror:1
    x = fmaxf(x, dpp_mov<0x122>(x));   // row_ror:2
    x = fmaxf(x, dpp_mov<0x124>(x));   // row_ror:4
    x = fmaxf(x, dpp_mov<0x128>(x));   // row_ror:8
    return x;
}
__device__ __forceinline__ float rowsum16(float x) {  // sum over 16-lane row
    x += dpp_mov<0x121>(x);
    x += dpp_mov<0x122>(x);
    x += dpp_mov<0x124>(x);
    x += dpp_mov<0x128>(x);
    return x;
}

// ---------------- fused cast fp32 -> split bf16 for xq and xc ----------------
__global__ __launch_bounds__(256) void k_cast_split2(const float* __restrict__ a,
                                                     const float* __restrict__ b,
                                                     u16* __restrict__ ah, u16* __restrict__ al,
                                                     u16* __restrict__ bh, u16* __restrict__ bl,
                                                     int n4each) {
    int i = blockIdx.x * 256 + threadIdx.x;
    const float* src; u16* dh; u16* dl; int j;
    if (i < n4each) { src = a; dh = ah; dl = al; j = i; }
    else            { src = b; dh = bh; dl = bl; j = i - n4each; }
    float4 v = reinterpret_cast<const float4*>(src)[j];
    ushort4 h, l;
    h.x = f2bf(v.x); l.x = f2bf(v.x - bf2f(h.x));
    h.y = f2bf(v.y); l.y = f2bf(v.y - bf2f(h.y));
    h.z = f2bf(v.z); l.z = f2bf(v.z - bf2f(h.z));
    h.w = f2bf(v.w); l.w = f2bf(v.w - bf2f(h.w));
    reinterpret_cast<ushort4*>(dh)[j] = h;
    reinterpret_cast<ushort4*>(dl)[j] = l;
}

// ---------------- transpose + cast: W (K x N fp32) -> WT (N x K bf16), plain ----------------
__global__ __launch_bounds__(256) void k_transpose_bf16(const float* __restrict__ W,
                                                        u16* __restrict__ WT,
                                                        int K, int N) {
    __shared__ float tile[32][33];
    int bn = blockIdx.x * 32;
    int bk = blockIdx.y * 32;
    int tx = threadIdx.x & 31;
    int ty = threadIdx.x >> 5;
#pragma unroll
    for (int i = 0; i < 32; i += 8)
        tile[ty + i][tx] = W[(size_t)(bk + ty + i) * N + bn + tx];
    __syncthreads();
#pragma unroll
    for (int i = 0; i < 32; i += 8)
        WT[(size_t)(bn + ty + i) * K + bk + tx] = f2bf(tile[tx][ty + i]);
}

// ---------------- transpose + split cast: W -> WT hi/lo ----------------
__global__ __launch_bounds__(256) void k_transpose_split(const float* __restrict__ W,
                                                         u16* __restrict__ WTh,
                                                         u16* __restrict__ WTl,
                                                         int K, int N) {
    __shared__ float tile[32][33];
    int bn = blockIdx.x * 32;
    int bk = blockIdx.y * 32;
    int tx = threadIdx.x & 31;
    int ty = threadIdx.x >> 5;
#pragma unroll
    for (int i = 0; i < 32; i += 8)
        tile[ty + i][tx] = W[(size_t)(bk + ty + i) * N + bn + tx];
    __syncthreads();
#pragma unroll
    for (int i = 0; i < 32; i += 8) {
        float x = tile[tx][ty + i];
        u16 h = f2bf(x);
        u16 l = f2bf(x - bf2f(h));
        WTh[(size_t)(bn + ty + i) * K + bk + tx] = h;
        WTl[(size_t)(bn + ty + i) * K + bk + tx] = l;
    }
}

// ---------------- plain GEMM mainloop: C(128x128) = A * Bt^T ----------------
__device__ __forceinline__ void gemm_mainloop(const u16* __restrict__ A,
                                              const u16* __restrict__ Bt,
                                              u16* As, u16* Bs,
                                              int tileM, int tileN, int K,
                                              f32x4 acc[4][4]) {
    const int tid = threadIdx.x;
    const int lane = tid & 63;
    const int wv = tid >> 6;
    const int wm = wv >> 1, wn = wv & 1;
    const int quad = lane >> 4, l15 = lane & 15;

    const int c0 = tid, c1 = tid + 256;
    const u16* Ap0 = A + (size_t)(tileM + (c0 >> 2)) * K + (c0 & 3) * 8;
    const u16* Ap1 = A + (size_t)(tileM + (c1 >> 2)) * K + (c1 & 3) * 8;
    const u16* Bp0 = Bt + (size_t)(tileN + (c0 >> 2)) * K + (c0 & 3) * 8;
    const u16* Bp1 = Bt + (size_t)(tileN + (c1 >> 2)) * K + (c1 & 3) * 8;

    for (int k0 = 0; k0 < K; k0 += 32) {
        __syncthreads();
        gl_lds16(Ap0 + k0, &As[c0 * 8]);
        gl_lds16(Ap1 + k0, &As[c1 * 8]);
        gl_lds16(Bp0 + k0, &Bs[c0 * 8]);
        gl_lds16(Bp1 + k0, &Bs[c1 * 8]);
        __syncthreads();
        bf16x8 af[4], bfr[4];
#pragma unroll
        for (int mi = 0; mi < 4; ++mi)
            af[mi] = ld8(&As[(wm * 64 + mi * 16 + l15) * 32 + quad * 8]);
#pragma unroll
        for (int ni = 0; ni < 4; ++ni)
            bfr[ni] = ld8(&Bs[(wn * 64 + ni * 16 + l15) * 32 + quad * 8]);
#pragma unroll
        for (int mi = 0; mi < 4; ++mi)
#pragma unroll
            for (int ni = 0; ni < 4; ++ni)
                acc[mi][ni] = __builtin_amdgcn_mfma_f32_16x16x32_bf16(
                    af[mi], bfr[ni], acc[mi][ni], 0, 0, 0);
    }
}

// ---------------- split GEMM mainloop: acc += Ah*Bh + Ah*Bl + Al*Bh ----------------
__device__ __forceinline__ void gemm_mainloop_split(const u16* __restrict__ Ah,
                                                    const u16* __restrict__ Al,
                                                    const u16* __restrict__ Bh,
                                                    const u16* __restrict__ Bl,
                                                    u16* Ash, u16* Asl, u16* Bsh, u16* Bsl,
                                                    int tileM, int tileN, int K,
                                                    f32x4 acc[4][4]) {
    const int tid = threadIdx.x;
    const int lane = tid & 63;
    const int wv = tid >> 6;
    const int wm = wv >> 1, wn = wv & 1;
    const int quad = lane >> 4, l15 = lane & 15;

    const int c0 = tid, c1 = tid + 256;
    const size_t ao0 = (size_t)(tileM + (c0 >> 2)) * K + (c0 & 3) * 8;
    const size_t ao1 = (size_t)(tileM + (c1 >> 2)) * K + (c1 & 3) * 8;
    const size_t bo0 = (size_t)(tileN + (c0 >> 2)) * K + (c0 & 3) * 8;
    const size_t bo1 = (size_t)(tileN + (c1 >> 2)) * K + (c1 & 3) * 8;

    for (int k0 = 0; k0 < K; k0 += 32) {
        __syncthreads();
        gl_lds16(Ah + ao0 + k0, &Ash[c0 * 8]);
        gl_lds16(Ah + ao1 + k0, &Ash[c1 * 8]);
        gl_lds16(Al + ao0 + k0, &Asl[c0 * 8]);
        gl_lds16(Al + ao1 + k0, &Asl[c1 * 8]);
        gl_lds16(Bh + bo0 + k0, &Bsh[c0 * 8]);
        gl_lds16(Bh + bo1 + k0, &Bsh[c1 * 8]);
        gl_lds16(Bl + bo0 + k0, &Bsl[c0 * 8]);
        gl_lds16(Bl + bo1 + k0, &Bsl[c1 * 8]);
        __syncthreads();
        bf16x8 afh[4], afl[4], bfh[4], bfl[4];
#pragma unroll
        for (int mi = 0; mi < 4; ++mi) {
            afh[mi] = ld8(&Ash[(wm * 64 + mi * 16 + l15) * 32 + quad * 8]);
            afl[mi] = ld8(&Asl[(wm * 64 + mi * 16 + l15) * 32 + quad * 8]);
        }
#pragma unroll
        for (int ni = 0; ni < 4; ++ni) {
            bfh[ni] = ld8(&Bsh[(wn * 64 + ni * 16 + l15) * 32 + quad * 8]);
            bfl[ni] = ld8(&Bsl[(wn * 64 + ni * 16 + l15) * 32 + quad * 8]);
        }
#pragma unroll
        for (int mi = 0; mi < 4; ++mi)
#pragma unroll
            for (int ni = 0; ni < 4; ++ni) {
                acc[mi][ni] = __builtin_amdgcn_mfma_f32_16x16x32_bf16(
                    afh[mi], bfh[ni], acc[mi][ni], 0, 0, 0);
                acc[mi][ni] = __builtin_amdgcn_mfma_f32_16x16x32_bf16(
                    afh[mi], bfl[ni], acc[mi][ni], 0, 0, 0);
                acc[mi][ni] = __builtin_amdgcn_mfma_f32_16x16x32_bf16(
                    afl[mi], bfh[ni], acc[mi][ni], 0, 0, 0);
            }
    }
}

#define ACC_INIT()                                                   \
    f32x4 acc[4][4];                                                 \
    _Pragma("unroll") for (int i = 0; i < 4; ++i)                    \
        _Pragma("unroll") for (int j = 0; j < 4; ++j)                \
            acc[i][j] = (f32x4){0.f, 0.f, 0.f, 0.f};

// ---------------- shared device body: Q/K (split+LN) and optional V (plain) ----------------
__device__ __forceinline__ void proj_qk_body(int bx, const u16* xq_h, const u16* xq_l,
                                             const u16* xc_h, const u16* xc_l,
                                             const u16* WqTh, const u16* WqTl,
                                             const u16* WkvTh, const u16* WkvTl,
                                             const float* lng, const float* lnb,
                                             u16* Qh_h, u16* Qh_l, u16* Kh_h, u16* Kh_l,
                                             u16* Ash, u16* Asl, u16* Bsh, u16* Bsl) {
    const bool isQ = bx < 8;
    const int tileM = blockIdx.y * 128, tileN = (bx & 7) * 128;
    const int tid = threadIdx.x;
    const int lane = tid & 63;
    const int wv = tid >> 6;
    const int wm = wv >> 1, wn = wv & 1;
    const int quad = lane >> 4, l15 = lane & 15;
    ACC_INIT();

    const u16* Ah = isQ ? xq_h : xc_h;
    const u16* Al = isQ ? xq_l : xc_l;
    const u16* Bh = isQ ? WqTh : WkvTh;
    const u16* Bl = isQ ? WqTl : WkvTl;
    u16* Dh = isQ ? Qh_h : Kh_h;
    u16* Dl = isQ ? Qh_l : Kh_l;
    const float scl = isQ ? 8.0f : 1.0f;

    gemm_mainloop_split(Ah, Al, Bh, Bl, Ash, Asl, Bsh, Bsl, tileM, tileN, D_MODEL, acc);

    float gv[4], bv[4];
#pragma unroll
    for (int ni = 0; ni < 4; ++ni) { gv[ni] = lng[ni * 16 + l15]; bv[ni] = lnb[ni * 16 + l15]; }

#pragma unroll
    for (int mi = 0; mi < 4; ++mi) {
#pragma unroll
        for (int r = 0; r < 4; ++r) {
            float sum = 0.f, sq = 0.f;
#pragma unroll
            for (int ni = 0; ni < 4; ++ni) { float x = acc[mi][ni][r]; sum += x; sq += x * x; }
            sum = rowsum16(sum);
            sq  = rowsum16(sq);
            float mu = sum * (1.f / 64.f);
            float var = sq * (1.f / 64.f) - mu * mu;
            float rs = rsqrtf(var + 1e-5f);
            int m = tileM + wm * 64 + mi * 16 + quad * 4 + r;
            int bb = m >> 11, n = m & (SEQ - 1);
#pragma unroll
            for (int ni = 0; ni < 4; ++ni) {
                int colg = tileN + wn * 64 + ni * 16 + l15;
                int h = colg >> 6;
                float y = ((acc[mi][ni][r] - mu) * rs * gv[ni] + bv[ni]) * scl;
                size_t idx = (((size_t)bb * NUM_HEADS + h) * SEQ + n) * HEAD_DIM + (colg & 63);
                u16 yh = f2bf(y);
                Dh[idx] = yh;
                Dl[idx] = f2bf(y - bf2f(yh));
            }
        }
    }
}

__device__ __forceinline__ void proj_v_body(int bxv, const u16* xc_h, const u16* WkvTh,
                                            u16* VT, u16* As, u16* Bs) {
    const int tileM = blockIdx.y * 128, tileN = D_MODEL + bxv * 128;
    const int tid = threadIdx.x;
    const int lane = tid & 63;
    const int wv = tid >> 6;
    const int wm = wv >> 1, wn = wv & 1;
    const int quad = lane >> 4, l15 = lane & 15;
    ACC_INIT();
    gemm_mainloop(xc_h, WkvTh, As, Bs, tileM, tileN, D_MODEL, acc);

#pragma unroll
    for (int mi = 0; mi < 4; ++mi) {
        int m0 = tileM + wm * 64 + mi * 16 + quad * 4;
        int bb = m0 >> 11, n0 = m0 & (SEQ - 1);
#pragma unroll
        for (int ni = 0; ni < 4; ++ni) {
            int colg = tileN + wn * 64 + ni * 16 + l15 - D_MODEL;
            int h = colg >> 6, d = colg & 63;
            ushort4 o;
            o.x = f2bf(acc[mi][ni][0]);
            o.y = f2bf(acc[mi][ni][1]);
            o.z = f2bf(acc[mi][ni][2]);
            o.w = f2bf(acc[mi][ni][3]);
            *reinterpret_cast<ushort4*>(
                &VT[(((size_t)bb * NUM_HEADS + h) * HEAD_DIM + d) * SEQ + n0]) = o;
        }
    }
}

// fused Q+K+V projection (requires VT not aliased with inputs)
__global__ __launch_bounds__(256) void k_proj_qkv(const u16* __restrict__ xq_h,
                                                  const u16* __restrict__ xq_l,
                                                  const u16* __restrict__ xc_h,
                                                  const u16* __restrict__ xc_l,
                                                  const u16* __restrict__ WqTh,
                                                  const u16* __restrict__ WqTl,
                                                  const u16* __restrict__ WkvTh,
                                                  const u16* __restrict__ WkvTl,
                                                  const float* __restrict__ lng,
                                                  const float* __restrict__ lnb,
                                                  u16* __restrict__ Qh_h,
                                                  u16* __restrict__ Qh_l,
                                                  u16* __restrict__ Kh_h,
                                                  u16* __restrict__ Kh_l,
                                                  u16* __restrict__ VT) {
    __shared__ __align__(16) u16 Ash[128 * 32], Asl[128 * 32];
    __shared__ __align__(16) u16 Bsh[128 * 32], Bsl[128 * 32];
    const int bx = blockIdx.x;
    if (bx < 16) {
        proj_qk_body(bx, xq_h, xq_l, xc_h, xc_l, WqTh, WqTl, WkvTh, WkvTl,
                     lng, lnb, Qh_h, Qh_l, Kh_h, Kh_l, Ash, Asl, Bsh, Bsl);
    } else {
        proj_v_body(bx - 16, xc_h, WkvTh, VT, Ash, Bsh);
    }
}

// fallback split kernels (VT aliased to xq_l — must not run in same kernel as Q-proj)
__global__ __launch_bounds__(256) void k_proj_qk(const u16* __restrict__ xq_h,
                                                 const u16* __restrict__ xq_l,
                                                 const u16* __restrict__ xc_h,
                                                 const u16* __restrict__ xc_l,
                                                 const u16* __restrict__ WqTh,
                                                 const u16* __restrict__ WqTl,
                                                 const u16* __restrict__ WkvTh,
                                                 const u16* __restrict__ WkvTl,
                                                 const float* __restrict__ lng,
                                                 const float* __restrict__ lnb,
                                                 u16* __restrict__ Qh_h,
                                                 u16* __restrict__ Qh_l,
                                                 u16* __restrict__ Kh_h,
                                                 u16* __restrict__ Kh_l) {
    __shared__ __align__(16) u16 Ash[128 * 32], Asl[128 * 32];
    __shared__ __align__(16) u16 Bsh[128 * 32], Bsl[128 * 32];
    proj_qk_body(blockIdx.x, xq_h, xq_l, xc_h, xc_l, WqTh, WqTl, WkvTh, WkvTl,
                 lng, lnb, Qh_h, Qh_l, Kh_h, Kh_l, Ash, Asl, Bsh, Bsl);
}
__global__ __launch_bounds__(256) void k_gemm_v(const u16* __restrict__ xc_h,
                                                const u16* __restrict__ WkvTh,
                                                u16* __restrict__ VT) {
    __shared__ __align__(16) u16 As[128 * 32];
    __shared__ __align__(16) u16 Bs[128 * 32];
    proj_v_body(blockIdx.x, xc_h, WkvTh, VT, As, Bs);
}

// ---------------- output projection + bias -> out fp32 (plain) ----------------
__global__ __launch_bounds__(256) void k_gemm_out(const u16* __restrict__ A,
                                                  const u16* __restrict__ Bt,
                                                  const float* __restrict__ bp,
                                                  float* __restrict__ out) {
    __shared__ __align__(16) u16 As[128 * 32];
    __shared__ __align__(16) u16 Bs[128 * 32];
    const int tileM = blockIdx.y * 128, tileN = blockIdx.x * 128;
    const int tid = threadIdx.x;
    const int lane = tid & 63;
    const int wv = tid >> 6;
    const int wm = wv >> 1, wn = wv & 1;
    const int quad = lane >> 4, l15 = lane & 15;
    ACC_INIT();
    gemm_mainloop(A, Bt, As, Bs, tileM, tileN, D_MODEL, acc);

    float bpv[4];
#pragma unroll
    for (int ni = 0; ni < 4; ++ni) bpv[ni] = bp[tileN + wn * 64 + ni * 16 + l15];
#pragma unroll
    for (int mi = 0; mi < 4; ++mi) {
#pragma unroll
        for (int r = 0; r < 4; ++r) {
            int m = tileM + wm * 64 + mi * 16 + quad * 4 + r;
#pragma unroll
            for (int ni = 0; ni < 4; ++ni) {
                int colg = tileN + wn * 64 + ni * 16 + l15;
                out[(size_t)m * D_MODEL + colg] = acc[mi][ni][r] + bpv[ni];
            }
        }
    }
}

// ---------------- flash attention: q-tile 64, 1024 blocks, 2 barriers/iter ----------------
// NO forced min-waves bound (round-3's __launch_bounds__(256,4) caused scratch
// spill: WRITE_SIZE 645 MB). LDS 36 KB -> 4 blocks/CU naturally.
// Each wave owns 16 q rows -> Ps round-trip is wave-private (no barrier).
// Split-bf16 Q,K: S = qh*kh + qh*kl + ql*kh. Softmax reductions via DPP (VALU pipe).
__global__ __launch_bounds__(256) void k_attn(const u16* __restrict__ Qh_h,
                                              const u16* __restrict__ Qh_l,
                                              const u16* __restrict__ Kh_h,
                                              const u16* __restrict__ Kh_l,
                                              const u16* __restrict__ VT,
                                              u16* __restrict__ AO) {
    __shared__ __align__(16) u16 Ksh[64 * 72];
    __shared__ __align__(16) u16 Ksl[64 * 72];
    __shared__ __align__(16) u16 Vs[64 * 72];
    __shared__ __align__(16) u16 Ps[64 * 72];

    const int tid = threadIdx.x;
    const int lane = tid & 63;
    const int wv = tid >> 6;               // wave owns q rows [wv*16, wv*16+16)
    const int quad = lane >> 4, l15 = lane & 15;
    const int qt = blockIdx.x;             // 0..31
    const int bh = blockIdx.y;             // 0..31

    const size_t bh_off = (size_t)bh * SEQ * HEAD_DIM;
    const u16* Qbh_h = Qh_h + bh_off;
    const u16* Qbh_l = Qh_l + bh_off;
    const u16* Vbh = VT + (size_t)bh * HEAD_DIM * SEQ;

    bf16x8 qfh[2], qfl[2];
#pragma unroll
    for (int kt = 0; kt < 2; ++kt) {
        size_t off = (size_t)(qt * 64 + wv * 16 + l15) * HEAD_DIM + kt * 32 + quad * 8;
        qfh[kt] = ld8(Qbh_h + off);
        qfl[kt] = ld8(Qbh_l + off);
    }

    f32x4 acc_o[4];
    float m_i[4], l_i[4];
#pragma unroll
    for (int ni = 0; ni < 4; ++ni) acc_o[ni] = (f32x4){0.f, 0.f, 0.f, 0.f};
#pragma unroll
    for (int r = 0; r < 4; ++r) { m_i[r] = -3.0e38f; l_i[r] = 0.f; }

    const uint4* Kgh = reinterpret_cast<const uint4*>(Kh_h + bh_off);
    const uint4* Kgl = reinterpret_cast<const uint4*>(Kh_l + bh_off);
    const uint4* Vg  = reinterpret_cast<const uint4*>(Vbh);

    for (int j = 0; j < SEQ / 64; ++j) {
        uint4 kregh[2], kregl[2], vreg[2];
#pragma unroll
        for (int i = 0; i < 2; ++i) {
            int c = tid + i * 256;
            kregh[i] = Kgh[(size_t)(j * 64 + (c >> 3)) * 8 + (c & 7)];
            kregl[i] = Kgl[(size_t)(j * 64 + (c >> 3)) * 8 + (c & 7)];
            vreg[i]  = Vg[(size_t)(c >> 3) * (SEQ / 8) + j * 8 + (c & 7)];
        }
        __syncthreads();
#pragma unroll
        for (int i = 0; i < 2; ++i) {
            int c = tid + i * 256;
            *reinterpret_cast<uint4*>(&Ksh[(c >> 3) * 72 + (c & 7) * 8]) = kregh[i];
            *reinterpret_cast<uint4*>(&Ksl[(c >> 3) * 72 + (c & 7) * 8]) = kregl[i];
            *reinterpret_cast<uint4*>(&Vs[(c >> 3) * 72 + (c & 7) * 8]) = vreg[i];
        }
        __syncthreads();

        // --- S = Q K^T (16 q rows x 64 keys per wave), split precision ---
        f32x4 acc_s[4];
#pragma unroll
        for (int ni = 0; ni < 4; ++ni) acc_s[ni] = (f32x4){0.f, 0.f, 0.f, 0.f};
#pragma unroll
        for (int kt = 0; kt < 2; ++kt) {
            bf16x8 kfh[4], kfl[4];
#pragma unroll
            for (int ni = 0; ni < 4; ++ni) {
                kfh[ni] = ld8(&Ksh[(ni * 16 + l15) * 72 + kt * 32 + quad * 8]);
                kfl[ni] = ld8(&Ksl[(ni * 16 + l15) * 72 + kt * 32 + quad * 8]);
            }
#pragma unroll
            for (int ni = 0; ni < 4; ++ni) {
                acc_s[ni] = __builtin_amdgcn_mfma_f32_16x16x32_bf16(
                    qfh[kt], kfh[ni], acc_s[ni], 0, 0, 0);
                acc_s[ni] = __builtin_amdgcn_mfma_f32_16x16x32_bf16(
                    qfh[kt], kfl[ni], acc_s[ni], 0, 0, 0);
                acc_s[ni] = __builtin_amdgcn_mfma_f32_16x16x32_bf16(
                    qfl[kt], kfh[ni], acc_s[ni], 0, 0, 0);
            }
        }

        // --- online softmax (DPP reductions on VALU pipe) ---
#pragma unroll
        for (int r = 0; r < 4; ++r) {
            float mx = fmaxf(fmaxf(acc_s[0][r], acc_s[1][r]),
                             fmaxf(acc_s[2][r], acc_s[3][r]));
            mx = rowmax16(mx);
            float mold = m_i[r];
            float mnew = fmaxf(mold, mx);
            float alpha = __expf(mold - mnew);
            float sum = 0.f;
            int rw = wv * 16 + quad * 4 + r;
#pragma unroll
            for (int ni = 0; ni < 4; ++ni) {
                float p = __expf(acc_s[ni][r] - mnew);
                uint32_t ub = __builtin_bit_cast(uint32_t, p) & 0xffff0000u;
                sum += __builtin_bit_cast(float, ub);           // l consistent with stored P
                Ps[rw * 72 + ni * 16 + l15] = (u16)(ub >> 16);  // truncation store
            }
            sum = rowsum16(sum);
            m_i[r] = mnew;
            l_i[r] = l_i[r] * alpha + sum;
#pragma unroll
            for (int ni = 0; ni < 4; ++ni) acc_o[ni][r] *= alpha;
        }
        // no barrier: each wave reads back only its own Ps rows

        // --- O += P V ---
#pragma unroll
        for (int kt = 0; kt < 2; ++kt) {
            bf16x8 pf = ld8(&Ps[(wv * 16 + l15) * 72 + kt * 32 + quad * 8]);
            bf16x8 vf[4];
#pragma unroll
            for (int ni = 0; ni < 4; ++ni)
                vf[ni] = ld8(&Vs[(ni * 16 + l15) * 72 + kt * 32 + quad * 8]);
#pragma unroll
            for (int ni = 0; ni < 4; ++ni)
                acc_o[ni] = __builtin_amdgcn_mfma_f32_16x16x32_bf16(
                    pf, vf[ni], acc_o[ni], 0, 0, 0);
        }
    }

    const int b = bh >> 4, h = bh & 15;
#pragma unroll
    for (int r = 0; r < 4; ++r) {
        float inv = 1.0f / l_i[r];
        int row = qt * 64 + wv * 16 + quad * 4 + r;
#pragma unroll
        for (int ni = 0; ni < 4; ++ni)
            AO[((size_t)(b * SEQ + row)) * D_MODEL + h * 64 + ni * 16 + l15] =
                f2bf(acc_o[ni][r] * inv);
    }
}

// ---------------- host ----------------
extern "C" void kernel_launch(void* const* d_in, const int* in_sizes, int n_in,
                              void* d_out, int out_size, void* d_ws, size_t ws_size,
                              hipStream_t stream) {
    const float* xq  = (const float*)d_in[0];
    const float* xc  = (const float*)d_in[1];
    const float* Wq  = (const float*)d_in[2];
    const float* Wkv = (const float*)d_in[3];
    const float* Wp  = (const float*)d_in[4];
    const float* bp  = (const float*)d_in[5];
    const float* lng = (const float*)d_in[6];
    const float* lnb = (const float*)d_in[7];
    float* out = (float*)d_out;

    char* ws = (char*)d_ws;
    const size_t MB = 1 << 20;
    u16* xq_h  = (u16*)(ws + 0 * MB);    // 8 MB
    u16* xq_l  = (u16*)(ws + 8 * MB);    // 8 MB
    u16* xc_h  = (u16*)(ws + 16 * MB);   // 8 MB
    u16* xc_l  = (u16*)(ws + 24 * MB);   // 8 MB
    u16* WqTh  = (u16*)(ws + 32 * MB);   // 2 MB
    u16* WqTl  = (u16*)(ws + 34 * MB);   // 2 MB
    u16* WkvTh = (u16*)(ws + 36 * MB);   // 4 MB
    u16* WkvTl = (u16*)(ws + 40 * MB);   // 4 MB
    u16* WpT   = (u16*)(ws + 44 * MB);   // 2 MB
    u16* Qh_h  = (u16*)(ws + 46 * MB);   // 8 MB
    u16* Qh_l  = (u16*)(ws + 54 * MB);   // 8 MB
    u16* Kh_h  = (u16*)(ws + 62 * MB);   // 8 MB
    u16* Kh_l  = (u16*)(ws + 70 * MB);   // 8 MB
    u16* AO = xq_h;   // alias: written by k_attn, xq_h dead after projections

    k_cast_split2<<<8192, 256, 0, stream>>>(xq, xc, xq_h, xq_l, xc_h, xc_l, 1048576);
    k_transpose_split<<<dim3(32, 32), 256, 0, stream>>>(Wq, WqTh, WqTl, 1024, 1024);
    k_transpose_split<<<dim3(64, 32), 256, 0, stream>>>(Wkv, WkvTh, WkvTl, 1024, 2048);
    k_transpose_bf16<<<dim3(32, 32), 256, 0, stream>>>(Wp, WpT, 1024, 1024);

    u16* VT;
    if (ws_size >= (size_t)86 * MB) {
        VT = (u16*)(ws + 78 * MB);   // dedicated 8 MB -> fused QKV projection
        k_proj_qkv<<<dim3(24, 32), 256, 0, stream>>>(xq_h, xq_l, xc_h, xc_l,
                                                     WqTh, WqTl, WkvTh, WkvTl,
                                                     lng, lnb, Qh_h, Qh_l, Kh_h, Kh_l, VT);
    } else {
        VT = xq_l;                   // alias safe only with the split launches
        k_proj_qk<<<dim3(16, 32), 256, 0, stream>>>(xq_h, xq_l, xc_h, xc_l,
                                                    WqTh, WqTl, WkvTh, WkvTl,
                                                    lng, lnb, Qh_h, Qh_l, Kh_h, Kh_l);
        k_gemm_v<<<dim3(8, 32), 256, 0, stream>>>(xc_h, WkvTh, VT);
    }
    k_attn<<<dim3(32, 32), 256, 0, stream>>>(Qh_h, Qh_l, Kh_h, Kh_l, VT, AO);
    k_gemm_out<<<dim3(8, 32), 256, 0, stream>>>(AO, WpT, bp, out);
}

// Round 5
// 424.742 us; speedup vs baseline: 1.0581x; 1.0581x over previous
//
#include <hip/hip_runtime.h>
#include <stdint.h>

#define NUM_HEADS 16
#define HEAD_DIM 64
#define D_MODEL 1024
#define SEQ 2048
#define BATCH 2

typedef unsigned short u16;
typedef __bf16 bf16x8 __attribute__((ext_vector_type(8)));
typedef float f32x4 __attribute__((ext_vector_type(4)));

__device__ __forceinline__ u16 f2bf(float f) {
    union { float f; uint32_t u; } v; v.f = f;
    uint32_t u = v.u;
    u += 0x7FFFu + ((u >> 16) & 1u);   // RNE
    return (u16)(u >> 16);
}
__device__ __forceinline__ float bf2f(u16 h) {
    union { uint32_t u; float f; } v; v.u = (uint32_t)h << 16; return v.f;
}

__device__ __forceinline__ bf16x8 ld8(const u16* p) {
    return *reinterpret_cast<const bf16x8*>(p);
}

__device__ __forceinline__ void gl_lds16(const void* g, void* l) {
    __builtin_amdgcn_global_load_lds(
        (const __attribute__((address_space(1))) void*)g,
        (__attribute__((address_space(3))) void*)l,
        16, 0, 0);
}

// ---- DPP 16-lane reductions (VALU pipe, not LDS pipe) ----
template <int CTRL>
__device__ __forceinline__ float dpp_mov(float x) {
    return __builtin_bit_cast(float,
        __builtin_amdgcn_update_dpp(0, __builtin_bit_cast(int, x), CTRL, 0xf, 0xf, true));
}
__device__ __forceinline__ float rowmax16(float x) {
    x = fmaxf(x, dpp_mov<0x121>(x));   // row_ror:1
    x = fmaxf(x, dpp_mov<0x122>(x));   // row_ror:2
    x = fmaxf(x, dpp_mov<0x124>(x));   // row_ror:4
    x = fmaxf(x, dpp_mov<0x128>(x));   // row_ror:8
    return x;
}
__device__ __forceinline__ float rowsum16(float x) {
    x += dpp_mov<0x121>(x);
    x += dpp_mov<0x122>(x);
    x += dpp_mov<0x124>(x);
    x += dpp_mov<0x128>(x);
    return x;
}

// ---------------- fused cast fp32 -> split bf16 for xq and xc ----------------
__global__ __launch_bounds__(256) void k_cast_split2(const float* __restrict__ a,
                                                     const float* __restrict__ b,
                                                     u16* __restrict__ ah, u16* __restrict__ al,
                                                     u16* __restrict__ bh, u16* __restrict__ bl,
                                                     int n4each) {
    int i = blockIdx.x * 256 + threadIdx.x;
    const float* src; u16* dh; u16* dl; int j;
    if (i < n4each) { src = a; dh = ah; dl = al; j = i; }
    else            { src = b; dh = bh; dl = bl; j = i - n4each; }
    float4 v = reinterpret_cast<const float4*>(src)[j];
    ushort4 h, l;
    h.x = f2bf(v.x); l.x = f2bf(v.x - bf2f(h.x));
    h.y = f2bf(v.y); l.y = f2bf(v.y - bf2f(h.y));
    h.z = f2bf(v.z); l.z = f2bf(v.z - bf2f(h.z));
    h.w = f2bf(v.w); l.w = f2bf(v.w - bf2f(h.w));
    reinterpret_cast<ushort4*>(dh)[j] = h;
    reinterpret_cast<ushort4*>(dl)[j] = l;
}

// ---------------- transpose + cast: W (K x N fp32) -> WT (N x K bf16), plain ----------------
__global__ __launch_bounds__(256) void k_transpose_bf16(const float* __restrict__ W,
                                                        u16* __restrict__ WT,
                                                        int K, int N) {
    __shared__ float tile[32][33];
    int bn = blockIdx.x * 32;
    int bk = blockIdx.y * 32;
    int tx = threadIdx.x & 31;
    int ty = threadIdx.x >> 5;
#pragma unroll
    for (int i = 0; i < 32; i += 8)
        tile[ty + i][tx] = W[(size_t)(bk + ty + i) * N + bn + tx];
    __syncthreads();
#pragma unroll
    for (int i = 0; i < 32; i += 8)
        WT[(size_t)(bn + ty + i) * K + bk + tx] = f2bf(tile[tx][ty + i]);
}

// ---------------- transpose + split cast: W -> WT hi/lo ----------------
__global__ __launch_bounds__(256) void k_transpose_split(const float* __restrict__ W,
                                                         u16* __restrict__ WTh,
                                                         u16* __restrict__ WTl,
                                                         int K, int N) {
    __shared__ float tile[32][33];
    int bn = blockIdx.x * 32;
    int bk = blockIdx.y * 32;
    int tx = threadIdx.x & 31;
    int ty = threadIdx.x >> 5;
#pragma unroll
    for (int i = 0; i < 32; i += 8)
        tile[ty + i][tx] = W[(size_t)(bk + ty + i) * N + bn + tx];
    __syncthreads();
#pragma unroll
    for (int i = 0; i < 32; i += 8) {
        float x = tile[tx][ty + i];
        u16 h = f2bf(x);
        u16 l = f2bf(x - bf2f(h));
        WTh[(size_t)(bn + ty + i) * K + bk + tx] = h;
        WTl[(size_t)(bn + ty + i) * K + bk + tx] = l;
    }
}

// ---------------- plain GEMM mainloop: C(128x128) = A * Bt^T ----------------
__device__ __forceinline__ void gemm_mainloop(const u16* __restrict__ A,
                                              const u16* __restrict__ Bt,
                                              u16* As, u16* Bs,
                                              int tileM, int tileN, int K,
                                              f32x4 acc[4][4]) {
    const int tid = threadIdx.x;
    const int lane = tid & 63;
    const int wv = tid >> 6;
    const int wm = wv >> 1, wn = wv & 1;
    const int quad = lane >> 4, l15 = lane & 15;

    const int c0 = tid, c1 = tid + 256;
    const u16* Ap0 = A + (size_t)(tileM + (c0 >> 2)) * K + (c0 & 3) * 8;
    const u16* Ap1 = A + (size_t)(tileM + (c1 >> 2)) * K + (c1 & 3) * 8;
    const u16* Bp0 = Bt + (size_t)(tileN + (c0 >> 2)) * K + (c0 & 3) * 8;
    const u16* Bp1 = Bt + (size_t)(tileN + (c1 >> 2)) * K + (c1 & 3) * 8;

    for (int k0 = 0; k0 < K; k0 += 32) {
        __syncthreads();
        gl_lds16(Ap0 + k0, &As[c0 * 8]);
        gl_lds16(Ap1 + k0, &As[c1 * 8]);
        gl_lds16(Bp0 + k0, &Bs[c0 * 8]);
        gl_lds16(Bp1 + k0, &Bs[c1 * 8]);
        __syncthreads();
        bf16x8 af[4], bfr[4];
#pragma unroll
        for (int mi = 0; mi < 4; ++mi)
            af[mi] = ld8(&As[(wm * 64 + mi * 16 + l15) * 32 + quad * 8]);
#pragma unroll
        for (int ni = 0; ni < 4; ++ni)
            bfr[ni] = ld8(&Bs[(wn * 64 + ni * 16 + l15) * 32 + quad * 8]);
#pragma unroll
        for (int mi = 0; mi < 4; ++mi)
#pragma unroll
            for (int ni = 0; ni < 4; ++ni)
                acc[mi][ni] = __builtin_amdgcn_mfma_f32_16x16x32_bf16(
                    af[mi], bfr[ni], acc[mi][ni], 0, 0, 0);
    }
}

// ---------------- split GEMM mainloop: acc += Ah*Bh + Ah*Bl + Al*Bh ----------------
__device__ __forceinline__ void gemm_mainloop_split(const u16* __restrict__ Ah,
                                                    const u16* __restrict__ Al,
                                                    const u16* __restrict__ Bh,
                                                    const u16* __restrict__ Bl,
                                                    u16* Ash, u16* Asl, u16* Bsh, u16* Bsl,
                                                    int tileM, int tileN, int K,
                                                    f32x4 acc[4][4]) {
    const int tid = threadIdx.x;
    const int lane = tid & 63;
    const int wv = tid >> 6;
    const int wm = wv >> 1, wn = wv & 1;
    const int quad = lane >> 4, l15 = lane & 15;

    const int c0 = tid, c1 = tid + 256;
    const size_t ao0 = (size_t)(tileM + (c0 >> 2)) * K + (c0 & 3) * 8;
    const size_t ao1 = (size_t)(tileM + (c1 >> 2)) * K + (c1 & 3) * 8;
    const size_t bo0 = (size_t)(tileN + (c0 >> 2)) * K + (c0 & 3) * 8;
    const size_t bo1 = (size_t)(tileN + (c1 >> 2)) * K + (c1 & 3) * 8;

    for (int k0 = 0; k0 < K; k0 += 32) {
        __syncthreads();
        gl_lds16(Ah + ao0 + k0, &Ash[c0 * 8]);
        gl_lds16(Ah + ao1 + k0, &Ash[c1 * 8]);
        gl_lds16(Al + ao0 + k0, &Asl[c0 * 8]);
        gl_lds16(Al + ao1 + k0, &Asl[c1 * 8]);
        gl_lds16(Bh + bo0 + k0, &Bsh[c0 * 8]);
        gl_lds16(Bh + bo1 + k0, &Bsh[c1 * 8]);
        gl_lds16(Bl + bo0 + k0, &Bsl[c0 * 8]);
        gl_lds16(Bl + bo1 + k0, &Bsl[c1 * 8]);
        __syncthreads();
        bf16x8 afh[4], afl[4], bfh[4], bfl[4];
#pragma unroll
        for (int mi = 0; mi < 4; ++mi) {
            afh[mi] = ld8(&Ash[(wm * 64 + mi * 16 + l15) * 32 + quad * 8]);
            afl[mi] = ld8(&Asl[(wm * 64 + mi * 16 + l15) * 32 + quad * 8]);
        }
#pragma unroll
        for (int ni = 0; ni < 4; ++ni) {
            bfh[ni] = ld8(&Bsh[(wn * 64 + ni * 16 + l15) * 32 + quad * 8]);
            bfl[ni] = ld8(&Bsl[(wn * 64 + ni * 16 + l15) * 32 + quad * 8]);
        }
#pragma unroll
        for (int mi = 0; mi < 4; ++mi)
#pragma unroll
            for (int ni = 0; ni < 4; ++ni) {
                acc[mi][ni] = __builtin_amdgcn_mfma_f32_16x16x32_bf16(
                    afh[mi], bfh[ni], acc[mi][ni], 0, 0, 0);
                acc[mi][ni] = __builtin_amdgcn_mfma_f32_16x16x32_bf16(
                    afh[mi], bfl[ni], acc[mi][ni], 0, 0, 0);
                acc[mi][ni] = __builtin_amdgcn_mfma_f32_16x16x32_bf16(
                    afl[mi], bfh[ni], acc[mi][ni], 0, 0, 0);
            }
    }
}

#define ACC_INIT()                                                   \
    f32x4 acc[4][4];                                                 \
    _Pragma("unroll") for (int i = 0; i < 4; ++i)                    \
        _Pragma("unroll") for (int j = 0; j < 4; ++j)                \
            acc[i][j] = (f32x4){0.f, 0.f, 0.f, 0.f};

// ---------------- shared device body: Q/K (split+LN) and V (plain) ----------------
__device__ __forceinline__ void proj_qk_body(int bx, const u16* xq_h, const u16* xq_l,
                                             const u16* xc_h, const u16* xc_l,
                                             const u16* WqTh, const u16* WqTl,
                                             const u16* WkvTh, const u16* WkvTl,
                                             const float* lng, const float* lnb,
                                             u16* Qh_h, u16* Qh_l, u16* Kh_h, u16* Kh_l,
                                             u16* Ash, u16* Asl, u16* Bsh, u16* Bsl) {
    const bool isQ = bx < 8;
    const int tileM = blockIdx.y * 128, tileN = (bx & 7) * 128;
    const int tid = threadIdx.x;
    const int lane = tid & 63;
    const int wv = tid >> 6;
    const int wm = wv >> 1, wn = wv & 1;
    const int quad = lane >> 4, l15 = lane & 15;
    ACC_INIT();

    const u16* Ah = isQ ? xq_h : xc_h;
    const u16* Al = isQ ? xq_l : xc_l;
    const u16* Bh = isQ ? WqTh : WkvTh;
    const u16* Bl = isQ ? WqTl : WkvTl;
    u16* Dh = isQ ? Qh_h : Kh_h;
    u16* Dl = isQ ? Qh_l : Kh_l;
    const float scl = isQ ? 8.0f : 1.0f;

    gemm_mainloop_split(Ah, Al, Bh, Bl, Ash, Asl, Bsh, Bsl, tileM, tileN, D_MODEL, acc);

    float gv[4], bv[4];
#pragma unroll
    for (int ni = 0; ni < 4; ++ni) { gv[ni] = lng[ni * 16 + l15]; bv[ni] = lnb[ni * 16 + l15]; }

#pragma unroll
    for (int mi = 0; mi < 4; ++mi) {
#pragma unroll
        for (int r = 0; r < 4; ++r) {
            float sum = 0.f, sq = 0.f;
#pragma unroll
            for (int ni = 0; ni < 4; ++ni) { float x = acc[mi][ni][r]; sum += x; sq += x * x; }
            sum = rowsum16(sum);
            sq  = rowsum16(sq);
            float mu = sum * (1.f / 64.f);
            float var = sq * (1.f / 64.f) - mu * mu;
            float rs = rsqrtf(var + 1e-5f);
            int m = tileM + wm * 64 + mi * 16 + quad * 4 + r;
            int bb = m >> 11, n = m & (SEQ - 1);
#pragma unroll
            for (int ni = 0; ni < 4; ++ni) {
                int colg = tileN + wn * 64 + ni * 16 + l15;
                int h = colg >> 6;
                float y = ((acc[mi][ni][r] - mu) * rs * gv[ni] + bv[ni]) * scl;
                size_t idx = (((size_t)bb * NUM_HEADS + h) * SEQ + n) * HEAD_DIM + (colg & 63);
                u16 yh = f2bf(y);
                Dh[idx] = yh;
                Dl[idx] = f2bf(y - bf2f(yh));
            }
        }
    }
}

__device__ __forceinline__ void proj_v_body(int bxv, const u16* xc_h, const u16* WkvTh,
                                            u16* VT, u16* As, u16* Bs) {
    const int tileM = blockIdx.y * 128, tileN = D_MODEL + bxv * 128;
    const int tid = threadIdx.x;
    const int lane = tid & 63;
    const int wv = tid >> 6;
    const int wm = wv >> 1, wn = wv & 1;
    const int quad = lane >> 4, l15 = lane & 15;
    ACC_INIT();
    gemm_mainloop(xc_h, WkvTh, As, Bs, tileM, tileN, D_MODEL, acc);

#pragma unroll
    for (int mi = 0; mi < 4; ++mi) {
        int m0 = tileM + wm * 64 + mi * 16 + quad * 4;
        int bb = m0 >> 11, n0 = m0 & (SEQ - 1);
#pragma unroll
        for (int ni = 0; ni < 4; ++ni) {
            int colg = tileN + wn * 64 + ni * 16 + l15 - D_MODEL;
            int h = colg >> 6, d = colg & 63;
            ushort4 o;
            o.x = f2bf(acc[mi][ni][0]);
            o.y = f2bf(acc[mi][ni][1]);
            o.z = f2bf(acc[mi][ni][2]);
            o.w = f2bf(acc[mi][ni][3]);
            *reinterpret_cast<ushort4*>(
                &VT[(((size_t)bb * NUM_HEADS + h) * HEAD_DIM + d) * SEQ + n0]) = o;
        }
    }
}

// fused Q+K+V projection (requires VT not aliased with inputs)
__global__ __launch_bounds__(256, 2) void k_proj_qkv(const u16* __restrict__ xq_h,
                                                     const u16* __restrict__ xq_l,
                                                     const u16* __restrict__ xc_h,
                                                     const u16* __restrict__ xc_l,
                                                     const u16* __restrict__ WqTh,
                                                     const u16* __restrict__ WqTl,
                                                     const u16* __restrict__ WkvTh,
                                                     const u16* __restrict__ WkvTl,
                                                     const float* __restrict__ lng,
                                                     const float* __restrict__ lnb,
                                                     u16* __restrict__ Qh_h,
                                                     u16* __restrict__ Qh_l,
                                                     u16* __restrict__ Kh_h,
                                                     u16* __restrict__ Kh_l,
                                                     u16* __restrict__ VT) {
    __shared__ __align__(16) u16 Ash[128 * 32], Asl[128 * 32];
    __shared__ __align__(16) u16 Bsh[128 * 32], Bsl[128 * 32];
    const int bx = blockIdx.x;
    if (bx < 16) {
        proj_qk_body(bx, xq_h, xq_l, xc_h, xc_l, WqTh, WqTl, WkvTh, WkvTl,
                     lng, lnb, Qh_h, Qh_l, Kh_h, Kh_l, Ash, Asl, Bsh, Bsl);
    } else {
        proj_v_body(bx - 16, xc_h, WkvTh, VT, Ash, Bsh);
    }
}

// fallback split kernels (VT aliased to xq_l — must not run in same kernel as Q-proj)
__global__ __launch_bounds__(256, 2) void k_proj_qk(const u16* __restrict__ xq_h,
                                                    const u16* __restrict__ xq_l,
                                                    const u16* __restrict__ xc_h,
                                                    const u16* __restrict__ xc_l,
                                                    const u16* __restrict__ WqTh,
                                                    const u16* __restrict__ WqTl,
                                                    const u16* __restrict__ WkvTh,
                                                    const u16* __restrict__ WkvTl,
                                                    const float* __restrict__ lng,
                                                    const float* __restrict__ lnb,
                                                    u16* __restrict__ Qh_h,
                                                    u16* __restrict__ Qh_l,
                                                    u16* __restrict__ Kh_h,
                                                    u16* __restrict__ Kh_l) {
    __shared__ __align__(16) u16 Ash[128 * 32], Asl[128 * 32];
    __shared__ __align__(16) u16 Bsh[128 * 32], Bsl[128 * 32];
    proj_qk_body(blockIdx.x, xq_h, xq_l, xc_h, xc_l, WqTh, WqTl, WkvTh, WkvTl,
                 lng, lnb, Qh_h, Qh_l, Kh_h, Kh_l, Ash, Asl, Bsh, Bsl);
}
__global__ __launch_bounds__(256, 2) void k_gemm_v(const u16* __restrict__ xc_h,
                                                   const u16* __restrict__ WkvTh,
                                                   u16* __restrict__ VT) {
    __shared__ __align__(16) u16 As[128 * 32];
    __shared__ __align__(16) u16 Bs[128 * 32];
    proj_v_body(blockIdx.x, xc_h, WkvTh, VT, As, Bs);
}

// ---------------- output projection + bias -> out fp32 (plain) ----------------
__global__ __launch_bounds__(256, 2) void k_gemm_out(const u16* __restrict__ A,
                                                     const u16* __restrict__ Bt,
                                                     const float* __restrict__ bp,
                                                     float* __restrict__ out) {
    __shared__ __align__(16) u16 As[128 * 32];
    __shared__ __align__(16) u16 Bs[128 * 32];
    const int tileM = blockIdx.y * 128, tileN = blockIdx.x * 128;
    const int tid = threadIdx.x;
    const int lane = tid & 63;
    const int wv = tid >> 6;
    const int wm = wv >> 1, wn = wv & 1;
    const int quad = lane >> 4, l15 = lane & 15;
    ACC_INIT();
    gemm_mainloop(A, Bt, As, Bs, tileM, tileN, D_MODEL, acc);

    float bpv[4];
#pragma unroll
    for (int ni = 0; ni < 4; ++ni) bpv[ni] = bp[tileN + wn * 64 + ni * 16 + l15];
#pragma unroll
    for (int mi = 0; mi < 4; ++mi) {
#pragma unroll
        for (int r = 0; r < 4; ++r) {
            int m = tileM + wm * 64 + mi * 16 + quad * 4 + r;
#pragma unroll
            for (int ni = 0; ni < 4; ++ni) {
                int colg = tileN + wn * 64 + ni * 16 + l15;
                out[(size_t)m * D_MODEL + colg] = acc[mi][ni][r] + bpv[ni];
            }
        }
    }
}

// ---------------- flash attention: q-tile 64, XCD-swizzled 1D grid ----------------
// __launch_bounds__(256, 2): raises the backend's occupancy-driven register cap
// to 256 so the 6 staged uint4 (live across the barrier) do NOT spill.
// (Rounds 3/4: LDS=36KB made the backend target 4 waves/EU -> 128-reg cap ->
//  arch-VGPR 64 -> 6 KB/wave-iter scratch spill -> WRITE_SIZE 785 MB.)
// XCD swizzle: id&7 carries bh&7 so all 32 q-tiles of a (b,h) share one XCD's L2.
__global__ __launch_bounds__(256, 2) void k_attn(const u16* __restrict__ Qh_h,
                                                 const u16* __restrict__ Qh_l,
                                                 const u16* __restrict__ Kh_h,
                                                 const u16* __restrict__ Kh_l,
                                                 const u16* __restrict__ VT,
                                                 u16* __restrict__ AO) {
    __shared__ __align__(16) u16 Ksh[64 * 72];
    __shared__ __align__(16) u16 Ksl[64 * 72];
    __shared__ __align__(16) u16 Vs[64 * 72];
    __shared__ __align__(16) u16 Ps[64 * 72];

    const int tid = threadIdx.x;
    const int lane = tid & 63;
    const int wv = tid >> 6;               // wave owns q rows [wv*16, wv*16+16)
    const int quad = lane >> 4, l15 = lane & 15;
    const int id = blockIdx.x;             // 0..1023
    const int bh = (id & 7) | (((id >> 8) & 3) << 3);
    const int qt = (id >> 3) & 31;

    const size_t bh_off = (size_t)bh * SEQ * HEAD_DIM;
    const u16* Qbh_h = Qh_h + bh_off;
    const u16* Qbh_l = Qh_l + bh_off;
    const u16* Vbh = VT + (size_t)bh * HEAD_DIM * SEQ;

    bf16x8 qfh[2], qfl[2];
#pragma unroll
    for (int kt = 0; kt < 2; ++kt) {
        size_t off = (size_t)(qt * 64 + wv * 16 + l15) * HEAD_DIM + kt * 32 + quad * 8;
        qfh[kt] = ld8(Qbh_h + off);
        qfl[kt] = ld8(Qbh_l + off);
    }

    f32x4 acc_o[4];
    float m_i[4], l_i[4];
#pragma unroll
    for (int ni = 0; ni < 4; ++ni) acc_o[ni] = (f32x4){0.f, 0.f, 0.f, 0.f};
#pragma unroll
    for (int r = 0; r < 4; ++r) { m_i[r] = -3.0e38f; l_i[r] = 0.f; }

    const uint4* Kgh = reinterpret_cast<const uint4*>(Kh_h + bh_off);
    const uint4* Kgl = reinterpret_cast<const uint4*>(Kh_l + bh_off);
    const uint4* Vg  = reinterpret_cast<const uint4*>(Vbh);

    for (int j = 0; j < SEQ / 64; ++j) {
        uint4 kregh[2], kregl[2], vreg[2];
#pragma unroll
        for (int i = 0; i < 2; ++i) {
            int c = tid + i * 256;
            kregh[i] = Kgh[(size_t)(j * 64 + (c >> 3)) * 8 + (c & 7)];
            kregl[i] = Kgl[(size_t)(j * 64 + (c >> 3)) * 8 + (c & 7)];
            vreg[i]  = Vg[(size_t)(c >> 3) * (SEQ / 8) + j * 8 + (c & 7)];
        }
        __syncthreads();
#pragma unroll
        for (int i = 0; i < 2; ++i) {
            int c = tid + i * 256;
            *reinterpret_cast<uint4*>(&Ksh[(c >> 3) * 72 + (c & 7) * 8]) = kregh[i];
            *reinterpret_cast<uint4*>(&Ksl[(c >> 3) * 72 + (c & 7) * 8]) = kregl[i];
            *reinterpret_cast<uint4*>(&Vs[(c >> 3) * 72 + (c & 7) * 8]) = vreg[i];
        }
        __syncthreads();

        // --- S = Q K^T (16 q rows x 64 keys per wave), split precision ---
        f32x4 acc_s[4];
#pragma unroll
        for (int ni = 0; ni < 4; ++ni) acc_s[ni] = (f32x4){0.f, 0.f, 0.f, 0.f};
#pragma unroll
        for (int kt = 0; kt < 2; ++kt) {
            bf16x8 kfh[4], kfl[4];
#pragma unroll
            for (int ni = 0; ni < 4; ++ni) {
                kfh[ni] = ld8(&Ksh[(ni * 16 + l15) * 72 + kt * 32 + quad * 8]);
                kfl[ni] = ld8(&Ksl[(ni * 16 + l15) * 72 + kt * 32 + quad * 8]);
            }
#pragma unroll
            for (int ni = 0; ni < 4; ++ni) {
                acc_s[ni] = __builtin_amdgcn_mfma_f32_16x16x32_bf16(
                    qfh[kt], kfh[ni], acc_s[ni], 0, 0, 0);
                acc_s[ni] = __builtin_amdgcn_mfma_f32_16x16x32_bf16(
                    qfh[kt], kfl[ni], acc_s[ni], 0, 0, 0);
                acc_s[ni] = __builtin_amdgcn_mfma_f32_16x16x32_bf16(
                    qfl[kt], kfh[ni], acc_s[ni], 0, 0, 0);
            }
        }

        // --- online softmax (DPP reductions on VALU pipe) ---
#pragma unroll
        for (int r = 0; r < 4; ++r) {
            float mx = fmaxf(fmaxf(acc_s[0][r], acc_s[1][r]),
                             fmaxf(acc_s[2][r], acc_s[3][r]));
            mx = rowmax16(mx);
            float mold = m_i[r];
            float mnew = fmaxf(mold, mx);
            float alpha = __expf(mold - mnew);
            float sum = 0.f;
            int rw = wv * 16 + quad * 4 + r;
#pragma unroll
            for (int ni = 0; ni < 4; ++ni) {
                float p = __expf(acc_s[ni][r] - mnew);
                uint32_t ub = __builtin_bit_cast(uint32_t, p) & 0xffff0000u;
                sum += __builtin_bit_cast(float, ub);           // l consistent with stored P
                Ps[rw * 72 + ni * 16 + l15] = (u16)(ub >> 16);  // truncation store
            }
            sum = rowsum16(sum);
            m_i[r] = mnew;
            l_i[r] = l_i[r] * alpha + sum;
#pragma unroll
            for (int ni = 0; ni < 4; ++ni) acc_o[ni][r] *= alpha;
        }
        // no barrier: each wave reads back only its own Ps rows

        // --- O += P V ---
#pragma unroll
        for (int kt = 0; kt < 2; ++kt) {
            bf16x8 pf = ld8(&Ps[(wv * 16 + l15) * 72 + kt * 32 + quad * 8]);
            bf16x8 vf[4];
#pragma unroll
            for (int ni = 0; ni < 4; ++ni)
                vf[ni] = ld8(&Vs[(ni * 16 + l15) * 72 + kt * 32 + quad * 8]);
#pragma unroll
            for (int ni = 0; ni < 4; ++ni)
                acc_o[ni] = __builtin_amdgcn_mfma_f32_16x16x32_bf16(
                    pf, vf[ni], acc_o[ni], 0, 0, 0);
        }
    }

    const int b = bh >> 4, h = bh & 15;
#pragma unroll
    for (int r = 0; r < 4; ++r) {
        float inv = 1.0f / l_i[r];
        int row = qt * 64 + wv * 16 + quad * 4 + r;
#pragma unroll
        for (int ni = 0; ni < 4; ++ni)
            AO[((size_t)(b * SEQ + row)) * D_MODEL + h * 64 + ni * 16 + l15] =
                f2bf(acc_o[ni][r] * inv);
    }
}

// ---------------- host ----------------
extern "C" void kernel_launch(void* const* d_in, const int* in_sizes, int n_in,
                              void* d_out, int out_size, void* d_ws, size_t ws_size,
                              hipStream_t stream) {
    const float* xq  = (const float*)d_in[0];
    const float* xc  = (const float*)d_in[1];
    const float* Wq  = (const float*)d_in[2];
    const float* Wkv = (const float*)d_in[3];
    const float* Wp  = (const float*)d_in[4];
    const float* bp  = (const float*)d_in[5];
    const float* lng = (const float*)d_in[6];
    const float* lnb = (const float*)d_in[7];
    float* out = (float*)d_out;

    char* ws = (char*)d_ws;
    const size_t MB = 1 << 20;
    u16* xq_h  = (u16*)(ws + 0 * MB);    // 8 MB
    u16* xq_l  = (u16*)(ws + 8 * MB);    // 8 MB
    u16* xc_h  = (u16*)(ws + 16 * MB);   // 8 MB
    u16* xc_l  = (u16*)(ws + 24 * MB);   // 8 MB
    u16* WqTh  = (u16*)(ws + 32 * MB);   // 2 MB
    u16* WqTl  = (u16*)(ws + 34 * MB);   // 2 MB
    u16* WkvTh = (u16*)(ws + 36 * MB);   // 4 MB
    u16* WkvTl = (u16*)(ws + 40 * MB);   // 4 MB
    u16* WpT   = (u16*)(ws + 44 * MB);   // 2 MB
    u16* Qh_h  = (u16*)(ws + 46 * MB);   // 8 MB
    u16* Qh_l  = (u16*)(ws + 54 * MB);   // 8 MB
    u16* Kh_h  = (u16*)(ws + 62 * MB);   // 8 MB
    u16* Kh_l  = (u16*)(ws + 70 * MB);   // 8 MB
    u16* AO = xq_h;   // alias: written by k_attn, xq_h dead after projections

    k_cast_split2<<<8192, 256, 0, stream>>>(xq, xc, xq_h, xq_l, xc_h, xc_l, 1048576);
    k_transpose_split<<<dim3(32, 32), 256, 0, stream>>>(Wq, WqTh, WqTl, 1024, 1024);
    k_transpose_split<<<dim3(64, 32), 256, 0, stream>>>(Wkv, WkvTh, WkvTl, 1024, 2048);
    k_transpose_bf16<<<dim3(32, 32), 256, 0, stream>>>(Wp, WpT, 1024, 1024);

    u16* VT;
    if (ws_size >= (size_t)86 * MB) {
        VT = (u16*)(ws + 78 * MB);   // dedicated 8 MB -> fused QKV projection
        k_proj_qkv<<<dim3(24, 32), 256, 0, stream>>>(xq_h, xq_l, xc_h, xc_l,
                                                     WqTh, WqTl, WkvTh, WkvTl,
                                                     lng, lnb, Qh_h, Qh_l, Kh_h, Kh_l, VT);
    } else {
        VT = xq_l;                   // alias safe only with the split launches
        k_proj_qk<<<dim3(16, 32), 256, 0, stream>>>(xq_h, xq_l, xc_h, xc_l,
                                                    WqTh, WqTl, WkvTh, WkvTl,
                                                    lng, lnb, Qh_h, Qh_l, Kh_h, Kh_l);
        k_gemm_v<<<dim3(8, 32), 256, 0, stream>>>(xc_h, WkvTh, VT);
    }
    k_attn<<<1024, 256, 0, stream>>>(Qh_h, Qh_l, Kh_h, Kh_l, VT, AO);
    k_gemm_out<<<dim3(8, 32), 256, 0, stream>>>(AO, WpT, bp, out);
}

// Round 6
// 300.406 us; speedup vs baseline: 1.4960x; 1.4139x over previous
//
#include <hip/hip_runtime.h>
#include <stdint.h>

#define NUM_HEADS 16
#define HEAD_DIM 64
#define D_MODEL 1024
#define SEQ 2048
#define BATCH 2

typedef unsigned short u16;
typedef __bf16 bf16x8 __attribute__((ext_vector_type(8)));
typedef float f32x4 __attribute__((ext_vector_type(4)));

__device__ __forceinline__ u16 f2bf(float f) {
    union { float f; uint32_t u; } v; v.f = f;
    uint32_t u = v.u;
    u += 0x7FFFu + ((u >> 16) & 1u);   // RNE
    return (u16)(u >> 16);
}
__device__ __forceinline__ float bf2f(u16 h) {
    union { uint32_t u; float f; } v; v.u = (uint32_t)h << 16; return v.f;
}

__device__ __forceinline__ bf16x8 ld8(const u16* p) {
    return *reinterpret_cast<const bf16x8*>(p);
}

__device__ __forceinline__ void gl_lds16(const void* g, void* l) {
    __builtin_amdgcn_global_load_lds(
        (const __attribute__((address_space(1))) void*)g,
        (__attribute__((address_space(3))) void*)l,
        16, 0, 0);
}

// ---- DPP 16-lane reductions (VALU pipe, not LDS pipe) ----
template <int CTRL>
__device__ __forceinline__ float dpp_mov(float x) {
    return __builtin_bit_cast(float,
        __builtin_amdgcn_update_dpp(0, __builtin_bit_cast(int, x), CTRL, 0xf, 0xf, true));
}
__device__ __forceinline__ float rowmax16(float x) {
    x = fmaxf(x, dpp_mov<0x121>(x));   // row_ror:1
    x = fmaxf(x, dpp_mov<0x122>(x));   // row_ror:2
    x = fmaxf(x, dpp_mov<0x124>(x));   // row_ror:4
    x = fmaxf(x, dpp_mov<0x128>(x));   // row_ror:8
    return x;
}
__device__ __forceinline__ float rowsum16(float x) {
    x += dpp_mov<0x121>(x);
    x += dpp_mov<0x122>(x);
    x += dpp_mov<0x124>(x);
    x += dpp_mov<0x128>(x);
    return x;
}

// ---------------- fused cast fp32 -> split bf16 for xq and xc ----------------
__global__ __launch_bounds__(256) void k_cast_split2(const float* __restrict__ a,
                                                     const float* __restrict__ b,
                                                     u16* __restrict__ ah, u16* __restrict__ al,
                                                     u16* __restrict__ bh, u16* __restrict__ bl,
                                                     int n4each) {
    int i = blockIdx.x * 256 + threadIdx.x;
    const float* src; u16* dh; u16* dl; int j;
    if (i < n4each) { src = a; dh = ah; dl = al; j = i; }
    else            { src = b; dh = bh; dl = bl; j = i - n4each; }
    float4 v = reinterpret_cast<const float4*>(src)[j];
    ushort4 h, l;
    h.x = f2bf(v.x); l.x = f2bf(v.x - bf2f(h.x));
    h.y = f2bf(v.y); l.y = f2bf(v.y - bf2f(h.y));
    h.z = f2bf(v.z); l.z = f2bf(v.z - bf2f(h.z));
    h.w = f2bf(v.w); l.w = f2bf(v.w - bf2f(h.w));
    reinterpret_cast<ushort4*>(dh)[j] = h;
    reinterpret_cast<ushort4*>(dl)[j] = l;
}

// ---------------- transpose + cast: W (K x N fp32) -> WT (N x K bf16), plain ----------------
__global__ __launch_bounds__(256) void k_transpose_bf16(const float* __restrict__ W,
                                                        u16* __restrict__ WT,
                                                        int K, int N) {
    __shared__ float tile[32][33];
    int bn = blockIdx.x * 32;
    int bk = blockIdx.y * 32;
    int tx = threadIdx.x & 31;
    int ty = threadIdx.x >> 5;
#pragma unroll
    for (int i = 0; i < 32; i += 8)
        tile[ty + i][tx] = W[(size_t)(bk + ty + i) * N + bn + tx];
    __syncthreads();
#pragma unroll
    for (int i = 0; i < 32; i += 8)
        WT[(size_t)(bn + ty + i) * K + bk + tx] = f2bf(tile[tx][ty + i]);
}

// ---------------- transpose + split cast: W -> WT hi/lo ----------------
__global__ __launch_bounds__(256) void k_transpose_split(const float* __restrict__ W,
                                                         u16* __restrict__ WTh,
                                                         u16* __restrict__ WTl,
                                                         int K, int N) {
    __shared__ float tile[32][33];
    int bn = blockIdx.x * 32;
    int bk = blockIdx.y * 32;
    int tx = threadIdx.x & 31;
    int ty = threadIdx.x >> 5;
#pragma unroll
    for (int i = 0; i < 32; i += 8)
        tile[ty + i][tx] = W[(size_t)(bk + ty + i) * N + bn + tx];
    __syncthreads();
#pragma unroll
    for (int i = 0; i < 32; i += 8) {
        float x = tile[tx][ty + i];
        u16 h = f2bf(x);
        u16 l = f2bf(x - bf2f(h));
        WTh[(size_t)(bn + ty + i) * K + bk + tx] = h;
        WTl[(size_t)(bn + ty + i) * K + bk + tx] = l;
    }
}

// ---------------- plain GEMM mainloop: C(128x128) = A * Bt^T ----------------
__device__ __forceinline__ void gemm_mainloop(const u16* __restrict__ A,
                                              const u16* __restrict__ Bt,
                                              u16* As, u16* Bs,
                                              int tileM, int tileN, int K,
                                              f32x4 acc[4][4]) {
    const int tid = threadIdx.x;
    const int lane = tid & 63;
    const int wv = tid >> 6;
    const int wm = wv >> 1, wn = wv & 1;
    const int quad = lane >> 4, l15 = lane & 15;

    const int c0 = tid, c1 = tid + 256;
    const u16* Ap0 = A + (size_t)(tileM + (c0 >> 2)) * K + (c0 & 3) * 8;
    const u16* Ap1 = A + (size_t)(tileM + (c1 >> 2)) * K + (c1 & 3) * 8;
    const u16* Bp0 = Bt + (size_t)(tileN + (c0 >> 2)) * K + (c0 & 3) * 8;
    const u16* Bp1 = Bt + (size_t)(tileN + (c1 >> 2)) * K + (c1 & 3) * 8;

    for (int k0 = 0; k0 < K; k0 += 32) {
        __syncthreads();
        gl_lds16(Ap0 + k0, &As[c0 * 8]);
        gl_lds16(Ap1 + k0, &As[c1 * 8]);
        gl_lds16(Bp0 + k0, &Bs[c0 * 8]);
        gl_lds16(Bp1 + k0, &Bs[c1 * 8]);
        __syncthreads();
        bf16x8 af[4], bfr[4];
#pragma unroll
        for (int mi = 0; mi < 4; ++mi)
            af[mi] = ld8(&As[(wm * 64 + mi * 16 + l15) * 32 + quad * 8]);
#pragma unroll
        for (int ni = 0; ni < 4; ++ni)
            bfr[ni] = ld8(&Bs[(wn * 64 + ni * 16 + l15) * 32 + quad * 8]);
#pragma unroll
        for (int mi = 0; mi < 4; ++mi)
#pragma unroll
            for (int ni = 0; ni < 4; ++ni)
                acc[mi][ni] = __builtin_amdgcn_mfma_f32_16x16x32_bf16(
                    af[mi], bfr[ni], acc[mi][ni], 0, 0, 0);
    }
}

// ---------------- split GEMM mainloop: acc += Ah*Bh + Ah*Bl + Al*Bh ----------------
__device__ __forceinline__ void gemm_mainloop_split(const u16* __restrict__ Ah,
                                                    const u16* __restrict__ Al,
                                                    const u16* __restrict__ Bh,
                                                    const u16* __restrict__ Bl,
                                                    u16* Ash, u16* Asl, u16* Bsh, u16* Bsl,
                                                    int tileM, int tileN, int K,
                                                    f32x4 acc[4][4]) {
    const int tid = threadIdx.x;
    const int lane = tid & 63;
    const int wv = tid >> 6;
    const int wm = wv >> 1, wn = wv & 1;
    const int quad = lane >> 4, l15 = lane & 15;

    const int c0 = tid, c1 = tid + 256;
    const size_t ao0 = (size_t)(tileM + (c0 >> 2)) * K + (c0 & 3) * 8;
    const size_t ao1 = (size_t)(tileM + (c1 >> 2)) * K + (c1 & 3) * 8;
    const size_t bo0 = (size_t)(tileN + (c0 >> 2)) * K + (c0 & 3) * 8;
    const size_t bo1 = (size_t)(tileN + (c1 >> 2)) * K + (c1 & 3) * 8;

    for (int k0 = 0; k0 < K; k0 += 32) {
        __syncthreads();
        gl_lds16(Ah + ao0 + k0, &Ash[c0 * 8]);
        gl_lds16(Ah + ao1 + k0, &Ash[c1 * 8]);
        gl_lds16(Al + ao0 + k0, &Asl[c0 * 8]);
        gl_lds16(Al + ao1 + k0, &Asl[c1 * 8]);
        gl_lds16(Bh + bo0 + k0, &Bsh[c0 * 8]);
        gl_lds16(Bh + bo1 + k0, &Bsh[c1 * 8]);
        gl_lds16(Bl + bo0 + k0, &Bsl[c0 * 8]);
        gl_lds16(Bl + bo1 + k0, &Bsl[c1 * 8]);
        __syncthreads();
        bf16x8 afh[4], afl[4], bfh[4], bfl[4];
#pragma unroll
        for (int mi = 0; mi < 4; ++mi) {
            afh[mi] = ld8(&Ash[(wm * 64 + mi * 16 + l15) * 32 + quad * 8]);
            afl[mi] = ld8(&Asl[(wm * 64 + mi * 16 + l15) * 32 + quad * 8]);
        }
#pragma unroll
        for (int ni = 0; ni < 4; ++ni) {
            bfh[ni] = ld8(&Bsh[(wn * 64 + ni * 16 + l15) * 32 + quad * 8]);
            bfl[ni] = ld8(&Bsl[(wn * 64 + ni * 16 + l15) * 32 + quad * 8]);
        }
#pragma unroll
        for (int mi = 0; mi < 4; ++mi)
#pragma unroll
            for (int ni = 0; ni < 4; ++ni) {
                acc[mi][ni] = __builtin_amdgcn_mfma_f32_16x16x32_bf16(
                    afh[mi], bfh[ni], acc[mi][ni], 0, 0, 0);
                acc[mi][ni] = __builtin_amdgcn_mfma_f32_16x16x32_bf16(
                    afh[mi], bfl[ni], acc[mi][ni], 0, 0, 0);
                acc[mi][ni] = __builtin_amdgcn_mfma_f32_16x16x32_bf16(
                    afl[mi], bfh[ni], acc[mi][ni], 0, 0, 0);
            }
    }
}

#define ACC_INIT()                                                   \
    f32x4 acc[4][4];                                                 \
    _Pragma("unroll") for (int i = 0; i < 4; ++i)                    \
        _Pragma("unroll") for (int j = 0; j < 4; ++j)                \
            acc[i][j] = (f32x4){0.f, 0.f, 0.f, 0.f};

// ---------------- shared device body: Q/K (split+LN) and V (plain) ----------------
__device__ __forceinline__ void proj_qk_body(int bx, const u16* xq_h, const u16* xq_l,
                                             const u16* xc_h, const u16* xc_l,
                                             const u16* WqTh, const u16* WqTl,
                                             const u16* WkvTh, const u16* WkvTl,
                                             const float* lng, const float* lnb,
                                             u16* Qh_h, u16* Qh_l, u16* Kh_h, u16* Kh_l,
                                             u16* Ash, u16* Asl, u16* Bsh, u16* Bsl) {
    const bool isQ = bx < 8;
    const int tileM = blockIdx.y * 128, tileN = (bx & 7) * 128;
    const int tid = threadIdx.x;
    const int lane = tid & 63;
    const int wv = tid >> 6;
    const int wm = wv >> 1, wn = wv & 1;
    const int quad = lane >> 4, l15 = lane & 15;
    ACC_INIT();

    const u16* Ah = isQ ? xq_h : xc_h;
    const u16* Al = isQ ? xq_l : xc_l;
    const u16* Bh = isQ ? WqTh : WkvTh;
    const u16* Bl = isQ ? WqTl : WkvTl;
    u16* Dh = isQ ? Qh_h : Kh_h;
    u16* Dl = isQ ? Qh_l : Kh_l;
    const float scl = isQ ? 8.0f : 1.0f;

    gemm_mainloop_split(Ah, Al, Bh, Bl, Ash, Asl, Bsh, Bsl, tileM, tileN, D_MODEL, acc);

    float gv[4], bv[4];
#pragma unroll
    for (int ni = 0; ni < 4; ++ni) { gv[ni] = lng[ni * 16 + l15]; bv[ni] = lnb[ni * 16 + l15]; }

#pragma unroll
    for (int mi = 0; mi < 4; ++mi) {
#pragma unroll
        for (int r = 0; r < 4; ++r) {
            float sum = 0.f, sq = 0.f;
#pragma unroll
            for (int ni = 0; ni < 4; ++ni) { float x = acc[mi][ni][r]; sum += x; sq += x * x; }
            sum = rowsum16(sum);
            sq  = rowsum16(sq);
            float mu = sum * (1.f / 64.f);
            float var = sq * (1.f / 64.f) - mu * mu;
            float rs = rsqrtf(var + 1e-5f);
            int m = tileM + wm * 64 + mi * 16 + quad * 4 + r;
            int bb = m >> 11, n = m & (SEQ - 1);
#pragma unroll
            for (int ni = 0; ni < 4; ++ni) {
                int colg = tileN + wn * 64 + ni * 16 + l15;
                int h = colg >> 6;
                float y = ((acc[mi][ni][r] - mu) * rs * gv[ni] + bv[ni]) * scl;
                size_t idx = (((size_t)bb * NUM_HEADS + h) * SEQ + n) * HEAD_DIM + (colg & 63);
                u16 yh = f2bf(y);
                Dh[idx] = yh;
                Dl[idx] = f2bf(y - bf2f(yh));
            }
        }
    }
}

__device__ __forceinline__ void proj_v_body(int bxv, const u16* xc_h, const u16* WkvTh,
                                            u16* VT, u16* As, u16* Bs) {
    const int tileM = blockIdx.y * 128, tileN = D_MODEL + bxv * 128;
    const int tid = threadIdx.x;
    const int lane = tid & 63;
    const int wv = tid >> 6;
    const int wm = wv >> 1, wn = wv & 1;
    const int quad = lane >> 4, l15 = lane & 15;
    ACC_INIT();
    gemm_mainloop(xc_h, WkvTh, As, Bs, tileM, tileN, D_MODEL, acc);

#pragma unroll
    for (int mi = 0; mi < 4; ++mi) {
        int m0 = tileM + wm * 64 + mi * 16 + quad * 4;
        int bb = m0 >> 11, n0 = m0 & (SEQ - 1);
#pragma unroll
        for (int ni = 0; ni < 4; ++ni) {
            int colg = tileN + wn * 64 + ni * 16 + l15 - D_MODEL;
            int h = colg >> 6, d = colg & 63;
            ushort4 o;
            o.x = f2bf(acc[mi][ni][0]);
            o.y = f2bf(acc[mi][ni][1]);
            o.z = f2bf(acc[mi][ni][2]);
            o.w = f2bf(acc[mi][ni][3]);
            *reinterpret_cast<ushort4*>(
                &VT[(((size_t)bb * NUM_HEADS + h) * HEAD_DIM + d) * SEQ + n0]) = o;
        }
    }
}

// fused Q+K+V projection (requires VT not aliased with inputs)
__global__ __launch_bounds__(256, 2) void k_proj_qkv(const u16* __restrict__ xq_h,
                                                     const u16* __restrict__ xq_l,
                                                     const u16* __restrict__ xc_h,
                                                     const u16* __restrict__ xc_l,
                                                     const u16* __restrict__ WqTh,
                                                     const u16* __restrict__ WqTl,
                                                     const u16* __restrict__ WkvTh,
                                                     const u16* __restrict__ WkvTl,
                                                     const float* __restrict__ lng,
                                                     const float* __restrict__ lnb,
                                                     u16* __restrict__ Qh_h,
                                                     u16* __restrict__ Qh_l,
                                                     u16* __restrict__ Kh_h,
                                                     u16* __restrict__ Kh_l,
                                                     u16* __restrict__ VT) {
    __shared__ __align__(16) u16 Ash[128 * 32], Asl[128 * 32];
    __shared__ __align__(16) u16 Bsh[128 * 32], Bsl[128 * 32];
    const int bx = blockIdx.x;
    if (bx < 16) {
        proj_qk_body(bx, xq_h, xq_l, xc_h, xc_l, WqTh, WqTl, WkvTh, WkvTl,
                     lng, lnb, Qh_h, Qh_l, Kh_h, Kh_l, Ash, Asl, Bsh, Bsl);
    } else {
        proj_v_body(bx - 16, xc_h, WkvTh, VT, Ash, Bsh);
    }
}

// fallback split kernels (VT aliased to xq_l — must not run in same kernel as Q-proj)
__global__ __launch_bounds__(256, 2) void k_proj_qk(const u16* __restrict__ xq_h,
                                                    const u16* __restrict__ xq_l,
                                                    const u16* __restrict__ xc_h,
                                                    const u16* __restrict__ xc_l,
                                                    const u16* __restrict__ WqTh,
                                                    const u16* __restrict__ WqTl,
                                                    const u16* __restrict__ WkvTh,
                                                    const u16* __restrict__ WkvTl,
                                                    const float* __restrict__ lng,
                                                    const float* __restrict__ lnb,
                                                    u16* __restrict__ Qh_h,
                                                    u16* __restrict__ Qh_l,
                                                    u16* __restrict__ Kh_h,
                                                    u16* __restrict__ Kh_l) {
    __shared__ __align__(16) u16 Ash[128 * 32], Asl[128 * 32];
    __shared__ __align__(16) u16 Bsh[128 * 32], Bsl[128 * 32];
    proj_qk_body(blockIdx.x, xq_h, xq_l, xc_h, xc_l, WqTh, WqTl, WkvTh, WkvTl,
                 lng, lnb, Qh_h, Qh_l, Kh_h, Kh_l, Ash, Asl, Bsh, Bsl);
}
__global__ __launch_bounds__(256, 2) void k_gemm_v(const u16* __restrict__ xc_h,
                                                   const u16* __restrict__ WkvTh,
                                                   u16* __restrict__ VT) {
    __shared__ __align__(16) u16 As[128 * 32];
    __shared__ __align__(16) u16 Bs[128 * 32];
    proj_v_body(blockIdx.x, xc_h, WkvTh, VT, As, Bs);
}

// ---------------- output projection + bias -> out fp32 (plain) ----------------
__global__ __launch_bounds__(256, 2) void k_gemm_out(const u16* __restrict__ A,
                                                     const u16* __restrict__ Bt,
                                                     const float* __restrict__ bp,
                                                     float* __restrict__ out) {
    __shared__ __align__(16) u16 As[128 * 32];
    __shared__ __align__(16) u16 Bs[128 * 32];
    const int tileM = blockIdx.y * 128, tileN = blockIdx.x * 128;
    const int tid = threadIdx.x;
    const int lane = tid & 63;
    const int wv = tid >> 6;
    const int wm = wv >> 1, wn = wv & 1;
    const int quad = lane >> 4, l15 = lane & 15;
    ACC_INIT();
    gemm_mainloop(A, Bt, As, Bs, tileM, tileN, D_MODEL, acc);

    float bpv[4];
#pragma unroll
    for (int ni = 0; ni < 4; ++ni) bpv[ni] = bp[tileN + wn * 64 + ni * 16 + l15];
#pragma unroll
    for (int mi = 0; mi < 4; ++mi) {
#pragma unroll
        for (int r = 0; r < 4; ++r) {
            int m = tileM + wm * 64 + mi * 16 + quad * 4 + r;
#pragma unroll
            for (int ni = 0; ni < 4; ++ni) {
                int colg = tileN + wn * 64 + ni * 16 + l15;
                out[(size_t)m * D_MODEL + colg] = acc[mi][ni][r] + bpv[ni];
            }
        }
    }
}

// ---------------- flash attention v3: global_load_lds staging (NO register staging,
// NO spill) + XOR-swizzled unpadded LDS tiles + XCD-swizzled 1D grid.
// Rounds 3-5 post-mortem: staged uint4 held across __syncthreads() spilled to
// scratch (WRITE_SIZE 776 MB = 24 KB/block-iter) because the backend caps regs
// at 128 (4 waves/EU from LDS=36KB) and launch_bounds min-occupancy cannot
// RAISE the cap. global_load_lds stages HBM->LDS directly with zero VGPRs.
// Swizzle: lane (rr=lane>>3, ss=lane&7) fetches chunk (ss^rr) of row rr, so
// fragment reads at slot (kt*4+quad)^(l15&7) are 2-way-max bank aliased (free).
__global__ __launch_bounds__(256) void k_attn(const u16* __restrict__ Qh_h,
                                              const u16* __restrict__ Qh_l,
                                              const u16* __restrict__ Kh_h,
                                              const u16* __restrict__ Kh_l,
                                              const u16* __restrict__ VT,
                                              u16* __restrict__ AO) {
    __shared__ __align__(16) u16 Ksh[64 * 64];
    __shared__ __align__(16) u16 Ksl[64 * 64];
    __shared__ __align__(16) u16 Vs[64 * 64];
    __shared__ __align__(16) u16 Ps[64 * 72];

    const int tid = threadIdx.x;
    const int lane = tid & 63;
    const int wv = tid >> 6;               // wave owns q rows [wv*16, wv*16+16)
    const int quad = lane >> 4, l15 = lane & 15;
    const int id = blockIdx.x;             // 0..1023
    const int bh = (id & 7) | (((id >> 8) & 3) << 3);  // bh&7 == XCD id
    const int qt = (id >> 3) & 31;

    const size_t bh_off = (size_t)bh * SEQ * HEAD_DIM;
    const u16* Qbh_h = Qh_h + bh_off;
    const u16* Qbh_l = Qh_l + bh_off;
    const u16* Vbh = VT + (size_t)bh * HEAD_DIM * SEQ;

    // Q fragments (A operand) from global: row = l15, k = kt*32+quad*8
    bf16x8 qfh[2], qfl[2];
#pragma unroll
    for (int kt = 0; kt < 2; ++kt) {
        size_t off = (size_t)(qt * 64 + wv * 16 + l15) * HEAD_DIM + kt * 32 + quad * 8;
        qfh[kt] = ld8(Qbh_h + off);
        qfl[kt] = ld8(Qbh_l + off);
    }

    // ---- global_load_lds staging pointers (wave covers tile rows [wv*16, wv*16+16)) ----
    const int rr = lane >> 3;              // row within 8-row group
    const int ss = lane & 7;               // chunk slot in LDS
    const int cc = ss ^ rr;                // chunk fetched from global (XOR swizzle)
    const int row0 = wv * 16 + rr;         // rows for call 0; call 1 = row0+8 (same cc)
    const u16* kh0 = Kh_h + bh_off + (size_t)row0 * HEAD_DIM + cc * 8;
    const u16* kl0 = Kh_l + bh_off + (size_t)row0 * HEAD_DIM + cc * 8;
    const u16* v0  = Vbh + (size_t)row0 * SEQ + cc * 8;
    u16* ldsK0h = &Ksh[(wv * 16) * 64];
    u16* ldsK1h = &Ksh[(wv * 16 + 8) * 64];
    u16* ldsK0l = &Ksl[(wv * 16) * 64];
    u16* ldsK1l = &Ksl[(wv * 16 + 8) * 64];
    u16* ldsV0  = &Vs[(wv * 16) * 64];
    u16* ldsV1  = &Vs[(wv * 16 + 8) * 64];

    f32x4 acc_o[4];
    float m_i[4], l_i[4];
#pragma unroll
    for (int ni = 0; ni < 4; ++ni) acc_o[ni] = (f32x4){0.f, 0.f, 0.f, 0.f};
#pragma unroll
    for (int r = 0; r < 4; ++r) { m_i[r] = -3.0e38f; l_i[r] = 0.f; }

    for (int j = 0; j < SEQ / 64; ++j) {
        __syncthreads();   // all waves done reading previous Ks/Vs
        // K tiles advance 64 rows (64*64 u16); V advances 64 cols
        gl_lds16(kh0 + (size_t)j * 64 * HEAD_DIM,            ldsK0h);
        gl_lds16(kh0 + (size_t)j * 64 * HEAD_DIM + 8 * HEAD_DIM, ldsK1h);
        gl_lds16(kl0 + (size_t)j * 64 * HEAD_DIM,            ldsK0l);
        gl_lds16(kl0 + (size_t)j * 64 * HEAD_DIM + 8 * HEAD_DIM, ldsK1l);
        gl_lds16(v0 + j * 64,                                 ldsV0);
        gl_lds16(v0 + j * 64 + (size_t)8 * SEQ,               ldsV1);
        __syncthreads();   // compiler drains vmcnt before barrier

        // --- S = Q K^T (16 q rows x 64 keys per wave), split precision ---
        f32x4 acc_s[4];
#pragma unroll
        for (int ni = 0; ni < 4; ++ni) acc_s[ni] = (f32x4){0.f, 0.f, 0.f, 0.f};
#pragma unroll
        for (int kt = 0; kt < 2; ++kt) {
            bf16x8 kfh[4], kfl[4];
#pragma unroll
            for (int ni = 0; ni < 4; ++ni) {
                int slot = (kt * 4 + quad) ^ (l15 & 7);
                kfh[ni] = ld8(&Ksh[(ni * 16 + l15) * 64 + slot * 8]);
                kfl[ni] = ld8(&Ksl[(ni * 16 + l15) * 64 + slot * 8]);
            }
#pragma unroll
            for (int ni = 0; ni < 4; ++ni) {
                acc_s[ni] = __builtin_amdgcn_mfma_f32_16x16x32_bf16(
                    qfh[kt], kfh[ni], acc_s[ni], 0, 0, 0);
                acc_s[ni] = __builtin_amdgcn_mfma_f32_16x16x32_bf16(
                    qfh[kt], kfl[ni], acc_s[ni], 0, 0, 0);
                acc_s[ni] = __builtin_amdgcn_mfma_f32_16x16x32_bf16(
                    qfl[kt], kfh[ni], acc_s[ni], 0, 0, 0);
            }
        }

        // --- online softmax (DPP reductions on VALU pipe) ---
#pragma unroll
        for (int r = 0; r < 4; ++r) {
            float mx = fmaxf(fmaxf(acc_s[0][r], acc_s[1][r]),
                             fmaxf(acc_s[2][r], acc_s[3][r]));
            mx = rowmax16(mx);
            float mold = m_i[r];
            float mnew = fmaxf(mold, mx);
            float alpha = __expf(mold - mnew);
            float sum = 0.f;
            int rw = wv * 16 + quad * 4 + r;
#pragma unroll
            for (int ni = 0; ni < 4; ++ni) {
                float p = __expf(acc_s[ni][r] - mnew);
                uint32_t ub = __builtin_bit_cast(uint32_t, p) & 0xffff0000u;
                sum += __builtin_bit_cast(float, ub);           // l consistent with stored P
                Ps[rw * 72 + ni * 16 + l15] = (u16)(ub >> 16);  // truncation store
            }
            sum = rowsum16(sum);
            m_i[r] = mnew;
            l_i[r] = l_i[r] * alpha + sum;
#pragma unroll
            for (int ni = 0; ni < 4; ++ni) acc_o[ni][r] *= alpha;
        }
        // no barrier: each wave reads back only its own Ps rows

        // --- O += P V ---
#pragma unroll
        for (int kt = 0; kt < 2; ++kt) {
            bf16x8 pf = ld8(&Ps[(wv * 16 + l15) * 72 + kt * 32 + quad * 8]);
            bf16x8 vf[4];
#pragma unroll
            for (int ni = 0; ni < 4; ++ni) {
                int slot = (kt * 4 + quad) ^ (l15 & 7);
                vf[ni] = ld8(&Vs[(ni * 16 + l15) * 64 + slot * 8]);
            }
#pragma unroll
            for (int ni = 0; ni < 4; ++ni)
                acc_o[ni] = __builtin_amdgcn_mfma_f32_16x16x32_bf16(
                    pf, vf[ni], acc_o[ni], 0, 0, 0);
        }
    }

    const int b = bh >> 4, h = bh & 15;
#pragma unroll
    for (int r = 0; r < 4; ++r) {
        float inv = 1.0f / l_i[r];
        int row = qt * 64 + wv * 16 + quad * 4 + r;
#pragma unroll
        for (int ni = 0; ni < 4; ++ni)
            AO[((size_t)(b * SEQ + row)) * D_MODEL + h * 64 + ni * 16 + l15] =
                f2bf(acc_o[ni][r] * inv);
    }
}

// ---------------- host ----------------
extern "C" void kernel_launch(void* const* d_in, const int* in_sizes, int n_in,
                              void* d_out, int out_size, void* d_ws, size_t ws_size,
                              hipStream_t stream) {
    const float* xq  = (const float*)d_in[0];
    const float* xc  = (const float*)d_in[1];
    const float* Wq  = (const float*)d_in[2];
    const float* Wkv = (const float*)d_in[3];
    const float* Wp  = (const float*)d_in[4];
    const float* bp  = (const float*)d_in[5];
    const float* lng = (const float*)d_in[6];
    const float* lnb = (const float*)d_in[7];
    float* out = (float*)d_out;

    char* ws = (char*)d_ws;
    const size_t MB = 1 << 20;
    u16* xq_h  = (u16*)(ws + 0 * MB);    // 8 MB
    u16* xq_l  = (u16*)(ws + 8 * MB);    // 8 MB
    u16* xc_h  = (u16*)(ws + 16 * MB);   // 8 MB
    u16* xc_l  = (u16*)(ws + 24 * MB);   // 8 MB
    u16* WqTh  = (u16*)(ws + 32 * MB);   // 2 MB
    u16* WqTl  = (u16*)(ws + 34 * MB);   // 2 MB
    u16* WkvTh = (u16*)(ws + 36 * MB);   // 4 MB
    u16* WkvTl = (u16*)(ws + 40 * MB);   // 4 MB
    u16* WpT   = (u16*)(ws + 44 * MB);   // 2 MB
    u16* Qh_h  = (u16*)(ws + 46 * MB);   // 8 MB
    u16* Qh_l  = (u16*)(ws + 54 * MB);   // 8 MB
    u16* Kh_h  = (u16*)(ws + 62 * MB);   // 8 MB
    u16* Kh_l  = (u16*)(ws + 70 * MB);   // 8 MB
    u16* AO = xq_h;   // alias: written by k_attn, xq_h dead after projections

    k_cast_split2<<<8192, 256, 0, stream>>>(xq, xc, xq_h, xq_l, xc_h, xc_l, 1048576);
    k_transpose_split<<<dim3(32, 32), 256, 0, stream>>>(Wq, WqTh, WqTl, 1024, 1024);
    k_transpose_split<<<dim3(64, 32), 256, 0, stream>>>(Wkv, WkvTh, WkvTl, 1024, 2048);
    k_transpose_bf16<<<dim3(32, 32), 256, 0, stream>>>(Wp, WpT, 1024, 1024);

    u16* VT;
    if (ws_size >= (size_t)86 * MB) {
        VT = (u16*)(ws + 78 * MB);   // dedicated 8 MB -> fused QKV projection
        k_proj_qkv<<<dim3(24, 32), 256, 0, stream>>>(xq_h, xq_l, xc_h, xc_l,
                                                     WqTh, WqTl, WkvTh, WkvTl,
                                                     lng, lnb, Qh_h, Qh_l, Kh_h, Kh_l, VT);
    } else {
        VT = xq_l;                   // alias safe only with the split launches
        k_proj_qk<<<dim3(16, 32), 256, 0, stream>>>(xq_h, xq_l, xc_h, xc_l,
                                                    WqTh, WqTl, WkvTh, WkvTl,
                                                    lng, lnb, Qh_h, Qh_l, Kh_h, Kh_l);
        k_gemm_v<<<dim3(8, 32), 256, 0, stream>>>(xc_h, WkvTh, VT);
    }
    k_attn<<<1024, 256, 0, stream>>>(Qh_h, Qh_l, Kh_h, Kh_l, VT, AO);
    k_gemm_out<<<dim3(8, 32), 256, 0, stream>>>(AO, WpT, bp, out);
}

// Round 7
// 277.586 us; speedup vs baseline: 1.6190x; 1.0822x over previous
//
#include <hip/hip_runtime.h>
#include <stdint.h>

#define NUM_HEADS 16
#define HEAD_DIM 64
#define D_MODEL 1024
#define SEQ 2048
#define BATCH 2

typedef unsigned short u16;
typedef __bf16 bf16x8 __attribute__((ext_vector_type(8)));
typedef _Float16 f16x8 __attribute__((ext_vector_type(8)));
typedef float f32x4 __attribute__((ext_vector_type(4)));

__device__ __forceinline__ u16 f2bf(float f) {
    union { float f; uint32_t u; } v; v.f = f;
    uint32_t u = v.u;
    u += 0x7FFFu + ((u >> 16) & 1u);   // RNE
    return (u16)(u >> 16);
}
__device__ __forceinline__ float bf2f(u16 h) {
    union { uint32_t u; float f; } v; v.u = (uint32_t)h << 16; return v.f;
}
__device__ __forceinline__ u16 f2h(float f) {
    _Float16 h = (_Float16)f;
    return __builtin_bit_cast(u16, h);
}

__device__ __forceinline__ bf16x8 ld8(const u16* p) {
    return *reinterpret_cast<const bf16x8*>(p);
}
__device__ __forceinline__ f16x8 ld8h(const u16* p) {
    return *reinterpret_cast<const f16x8*>(p);
}

__device__ __forceinline__ void gl_lds16(const void* g, void* l) {
    __builtin_amdgcn_global_load_lds(
        (const __attribute__((address_space(1))) void*)g,
        (__attribute__((address_space(3))) void*)l,
        16, 0, 0);
}

// ---- DPP 16-lane reductions (VALU pipe) ----
template <int CTRL>
__device__ __forceinline__ float dpp_mov(float x) {
    return __builtin_bit_cast(float,
        __builtin_amdgcn_update_dpp(0, __builtin_bit_cast(int, x), CTRL, 0xf, 0xf, true));
}
__device__ __forceinline__ float rowsum16(float x) {
    x += dpp_mov<0x121>(x);
    x += dpp_mov<0x122>(x);
    x += dpp_mov<0x124>(x);
    x += dpp_mov<0x128>(x);
    return x;
}

// ---------------- cast fp32 -> fp16 for xq and xc (one launch) ----------------
__global__ __launch_bounds__(256) void k_cast_f16(const float* __restrict__ a,
                                                  const float* __restrict__ b,
                                                  u16* __restrict__ a16,
                                                  u16* __restrict__ b16, int n4each) {
    int i = blockIdx.x * 256 + threadIdx.x;
    const float* src; u16* dst; int j;
    if (i < n4each) { src = a; dst = a16; j = i; }
    else            { src = b; dst = b16; j = i - n4each; }
    float4 v = reinterpret_cast<const float4*>(src)[j];
    ushort4 o;
    o.x = f2h(v.x); o.y = f2h(v.y); o.z = f2h(v.z); o.w = f2h(v.w);
    reinterpret_cast<ushort4*>(dst)[j] = o;
}

// ---------------- transpose + cast: W (K x N fp32) -> WT (N x K), bf16 or fp16 ----------------
__global__ __launch_bounds__(256) void k_transpose_bf16(const float* __restrict__ W,
                                                        u16* __restrict__ WT,
                                                        int K, int N) {
    __shared__ float tile[32][33];
    int bn = blockIdx.x * 32;
    int bk = blockIdx.y * 32;
    int tx = threadIdx.x & 31;
    int ty = threadIdx.x >> 5;
#pragma unroll
    for (int i = 0; i < 32; i += 8)
        tile[ty + i][tx] = W[(size_t)(bk + ty + i) * N + bn + tx];
    __syncthreads();
#pragma unroll
    for (int i = 0; i < 32; i += 8)
        WT[(size_t)(bn + ty + i) * K + bk + tx] = f2bf(tile[tx][ty + i]);
}
__global__ __launch_bounds__(256) void k_transpose_f16(const float* __restrict__ W,
                                                       u16* __restrict__ WT,
                                                       int K, int N) {
    __shared__ float tile[32][33];
    int bn = blockIdx.x * 32;
    int bk = blockIdx.y * 32;
    int tx = threadIdx.x & 31;
    int ty = threadIdx.x >> 5;
#pragma unroll
    for (int i = 0; i < 32; i += 8)
        tile[ty + i][tx] = W[(size_t)(bk + ty + i) * N + bn + tx];
    __syncthreads();
#pragma unroll
    for (int i = 0; i < 32; i += 8)
        WT[(size_t)(bn + ty + i) * K + bk + tx] = f2h(tile[tx][ty + i]);
}

// ---------------- bf16 GEMM mainloop (used by out-projection) ----------------
__device__ __forceinline__ void gemm_mainloop(const u16* __restrict__ A,
                                              const u16* __restrict__ Bt,
                                              u16* As, u16* Bs,
                                              int tileM, int tileN, int K,
                                              f32x4 acc[4][4]) {
    const int tid = threadIdx.x;
    const int lane = tid & 63;
    const int wv = tid >> 6;
    const int wm = wv >> 1, wn = wv & 1;
    const int quad = lane >> 4, l15 = lane & 15;

    const int c0 = tid, c1 = tid + 256;
    const u16* Ap0 = A + (size_t)(tileM + (c0 >> 2)) * K + (c0 & 3) * 8;
    const u16* Ap1 = A + (size_t)(tileM + (c1 >> 2)) * K + (c1 & 3) * 8;
    const u16* Bp0 = Bt + (size_t)(tileN + (c0 >> 2)) * K + (c0 & 3) * 8;
    const u16* Bp1 = Bt + (size_t)(tileN + (c1 >> 2)) * K + (c1 & 3) * 8;

    for (int k0 = 0; k0 < K; k0 += 32) {
        __syncthreads();
        gl_lds16(Ap0 + k0, &As[c0 * 8]);
        gl_lds16(Ap1 + k0, &As[c1 * 8]);
        gl_lds16(Bp0 + k0, &Bs[c0 * 8]);
        gl_lds16(Bp1 + k0, &Bs[c1 * 8]);
        __syncthreads();
        bf16x8 af[4], bfr[4];
#pragma unroll
        for (int mi = 0; mi < 4; ++mi)
            af[mi] = ld8(&As[(wm * 64 + mi * 16 + l15) * 32 + quad * 8]);
#pragma unroll
        for (int ni = 0; ni < 4; ++ni)
            bfr[ni] = ld8(&Bs[(wn * 64 + ni * 16 + l15) * 32 + quad * 8]);
#pragma unroll
        for (int mi = 0; mi < 4; ++mi)
#pragma unroll
            for (int ni = 0; ni < 4; ++ni)
                acc[mi][ni] = __builtin_amdgcn_mfma_f32_16x16x32_bf16(
                    af[mi], bfr[ni], acc[mi][ni], 0, 0, 0);
    }
}

// ---------------- fp16 GEMM mainloop (projections; input rounding 2^-11) ----------------
__device__ __forceinline__ void gemm_mainloop_f16(const u16* __restrict__ A,
                                                  const u16* __restrict__ Bt,
                                                  u16* As, u16* Bs,
                                                  int tileM, int tileN, int K,
                                                  f32x4 acc[4][4]) {
    const int tid = threadIdx.x;
    const int lane = tid & 63;
    const int wv = tid >> 6;
    const int wm = wv >> 1, wn = wv & 1;
    const int quad = lane >> 4, l15 = lane & 15;

    const int c0 = tid, c1 = tid + 256;
    const u16* Ap0 = A + (size_t)(tileM + (c0 >> 2)) * K + (c0 & 3) * 8;
    const u16* Ap1 = A + (size_t)(tileM + (c1 >> 2)) * K + (c1 & 3) * 8;
    const u16* Bp0 = Bt + (size_t)(tileN + (c0 >> 2)) * K + (c0 & 3) * 8;
    const u16* Bp1 = Bt + (size_t)(tileN + (c1 >> 2)) * K + (c1 & 3) * 8;

    for (int k0 = 0; k0 < K; k0 += 32) {
        __syncthreads();
        gl_lds16(Ap0 + k0, &As[c0 * 8]);
        gl_lds16(Ap1 + k0, &As[c1 * 8]);
        gl_lds16(Bp0 + k0, &Bs[c0 * 8]);
        gl_lds16(Bp1 + k0, &Bs[c1 * 8]);
        __syncthreads();
        f16x8 af[4], bfr[4];
#pragma unroll
        for (int mi = 0; mi < 4; ++mi)
            af[mi] = ld8h(&As[(wm * 64 + mi * 16 + l15) * 32 + quad * 8]);
#pragma unroll
        for (int ni = 0; ni < 4; ++ni)
            bfr[ni] = ld8h(&Bs[(wn * 64 + ni * 16 + l15) * 32 + quad * 8]);
#pragma unroll
        for (int mi = 0; mi < 4; ++mi)
#pragma unroll
            for (int ni = 0; ni < 4; ++ni)
                acc[mi][ni] = __builtin_amdgcn_mfma_f32_16x16x32_f16(
                    af[mi], bfr[ni], acc[mi][ni], 0, 0, 0);
    }
}

#define ACC_INIT()                                                   \
    f32x4 acc[4][4];                                                 \
    _Pragma("unroll") for (int i = 0; i < 4; ++i)                    \
        _Pragma("unroll") for (int j = 0; j < 4; ++j)                \
            acc[i][j] = (f32x4){0.f, 0.f, 0.f, 0.f};

// ---------------- fused QKV projection (fp16 GEMM): Q/K -> LN + split-bf16, V -> bf16 VT ----------------
// blockIdx.x: [0,8) Q tiles, [8,16) K tiles, [16,24) V tiles. blockIdx.y = M tile.
__global__ __launch_bounds__(256, 2) void k_proj_f16(const u16* __restrict__ xq16,
                                                     const u16* __restrict__ xc16,
                                                     const u16* __restrict__ WqT16,
                                                     const u16* __restrict__ WkvT16,
                                                     const float* __restrict__ lng,
                                                     const float* __restrict__ lnb,
                                                     u16* __restrict__ Qh_h,
                                                     u16* __restrict__ Qh_l,
                                                     u16* __restrict__ Kh_h,
                                                     u16* __restrict__ Kh_l,
                                                     u16* __restrict__ VT) {
    __shared__ __align__(16) u16 As[128 * 32];
    __shared__ __align__(16) u16 Bs[128 * 32];
    const int bx = blockIdx.x;
    const int tileM = blockIdx.y * 128;
    const int tid = threadIdx.x;
    const int lane = tid & 63;
    const int wv = tid >> 6;
    const int wm = wv >> 1, wn = wv & 1;
    const int quad = lane >> 4, l15 = lane & 15;
    ACC_INIT();

    if (bx < 16) {   // Q or K: fp16 GEMM + LayerNorm + split-bf16 store
        const bool isQ = bx < 8;
        const int tileN = (bx & 7) * 128;
        const u16* Axx = isQ ? xq16 : xc16;
        const u16* Bt  = isQ ? WqT16 : WkvT16;
        u16* Dh = isQ ? Qh_h : Kh_h;
        u16* Dl = isQ ? Qh_l : Kh_l;
        const float scl = isQ ? 8.0f : 1.0f;

        gemm_mainloop_f16(Axx, Bt, As, Bs, tileM, tileN, D_MODEL, acc);

        float gv[4], bv[4];
#pragma unroll
        for (int ni = 0; ni < 4; ++ni) { gv[ni] = lng[ni * 16 + l15]; bv[ni] = lnb[ni * 16 + l15]; }

#pragma unroll
        for (int mi = 0; mi < 4; ++mi) {
#pragma unroll
            for (int r = 0; r < 4; ++r) {
                float sum = 0.f, sq = 0.f;
#pragma unroll
                for (int ni = 0; ni < 4; ++ni) { float x = acc[mi][ni][r]; sum += x; sq += x * x; }
                sum = rowsum16(sum);
                sq  = rowsum16(sq);
                float mu = sum * (1.f / 64.f);
                float var = sq * (1.f / 64.f) - mu * mu;
                float rs = rsqrtf(var + 1e-5f);
                int m = tileM + wm * 64 + mi * 16 + quad * 4 + r;
                int bb = m >> 11, n = m & (SEQ - 1);
#pragma unroll
                for (int ni = 0; ni < 4; ++ni) {
                    int colg = tileN + wn * 64 + ni * 16 + l15;
                    int h = colg >> 6;
                    float y = ((acc[mi][ni][r] - mu) * rs * gv[ni] + bv[ni]) * scl;
                    size_t idx = (((size_t)bb * NUM_HEADS + h) * SEQ + n) * HEAD_DIM + (colg & 63);
                    u16 yh = f2bf(y);
                    Dh[idx] = yh;
                    Dl[idx] = f2bf(y - bf2f(yh));
                }
            }
        }
    } else {         // V: fp16 GEMM, store bf16 transposed (d-major)
        const int tileN = D_MODEL + (bx - 16) * 128;
        gemm_mainloop_f16(xc16, WkvT16, As, Bs, tileM, tileN, D_MODEL, acc);
#pragma unroll
        for (int mi = 0; mi < 4; ++mi) {
            int m0 = tileM + wm * 64 + mi * 16 + quad * 4;
            int bb = m0 >> 11, n0 = m0 & (SEQ - 1);
#pragma unroll
            for (int ni = 0; ni < 4; ++ni) {
                int colg = tileN + wn * 64 + ni * 16 + l15 - D_MODEL;
                int h = colg >> 6, d = colg & 63;
                ushort4 o;
                o.x = f2bf(acc[mi][ni][0]);
                o.y = f2bf(acc[mi][ni][1]);
                o.z = f2bf(acc[mi][ni][2]);
                o.w = f2bf(acc[mi][ni][3]);
                *reinterpret_cast<ushort4*>(
                    &VT[(((size_t)bb * NUM_HEADS + h) * HEAD_DIM + d) * SEQ + n0]) = o;
            }
        }
    }
}

// ---------------- output projection + bias -> out fp32 (bf16 GEMM) ----------------
__global__ __launch_bounds__(256, 2) void k_gemm_out(const u16* __restrict__ A,
                                                     const u16* __restrict__ Bt,
                                                     const float* __restrict__ bp,
                                                     float* __restrict__ out) {
    __shared__ __align__(16) u16 As[128 * 32];
    __shared__ __align__(16) u16 Bs[128 * 32];
    const int tileM = blockIdx.y * 128, tileN = blockIdx.x * 128;
    const int tid = threadIdx.x;
    const int lane = tid & 63;
    const int wv = tid >> 6;
    const int wm = wv >> 1, wn = wv & 1;
    const int quad = lane >> 4, l15 = lane & 15;
    ACC_INIT();
    gemm_mainloop(A, Bt, As, Bs, tileM, tileN, D_MODEL, acc);

    float bpv[4];
#pragma unroll
    for (int ni = 0; ni < 4; ++ni) bpv[ni] = bp[tileN + wn * 64 + ni * 16 + l15];
#pragma unroll
    for (int mi = 0; mi < 4; ++mi) {
#pragma unroll
        for (int r = 0; r < 4; ++r) {
            int m = tileM + wm * 64 + mi * 16 + quad * 4 + r;
#pragma unroll
            for (int ni = 0; ni < 4; ++ni) {
                int colg = tileN + wn * 64 + ni * 16 + l15;
                out[(size_t)m * D_MODEL + colg] = acc[mi][ni][r] + bpv[ni];
            }
        }
    }
}

// ---------------- flash attention v4: S^T layout ----------------
// Sᵀ = K·Qᵀ (operand swap; fragment loads unchanged): each lane holds all 16
// scores of ONE q column -> softmax = 15 in-reg ops + 2 shfl_xor; alpha/m/l
// go from x4 to x1 per lane. PV as Oᵀ = Vᵀ·Pᵀ (V loads unchanged). Pᵀ packs
// as 4x b64 LDS writes. Numerics identical to v3.
// Staging: global_load_lds (zero staging VGPRs -> no spill), XOR chunk swizzle,
// XCD-swizzled 1D grid (bh&7 = XCD).
__global__ __launch_bounds__(256) void k_attn(const u16* __restrict__ Qh_h,
                                              const u16* __restrict__ Qh_l,
                                              const u16* __restrict__ Kh_h,
                                              const u16* __restrict__ Kh_l,
                                              const u16* __restrict__ VT,
                                              u16* __restrict__ AO) {
    __shared__ __align__(16) u16 Ksh[64 * 64];
    __shared__ __align__(16) u16 Ksl[64 * 64];
    __shared__ __align__(16) u16 Vs[64 * 64];
    __shared__ __align__(16) u16 Ps[64 * 72];

    const int tid = threadIdx.x;
    const int lane = tid & 63;
    const int wv = tid >> 6;               // wave owns q cols [wv*16, wv*16+16)
    const int quad = lane >> 4, l15 = lane & 15;
    const int id = blockIdx.x;             // 0..1023
    const int bh = (id & 7) | (((id >> 8) & 3) << 3);  // bh&7 == XCD id
    const int qt = (id >> 3) & 31;

    const size_t bh_off = (size_t)bh * SEQ * HEAD_DIM;
    const u16* Qbh_h = Qh_h + bh_off;
    const u16* Qbh_l = Qh_l + bh_off;
    const u16* Vbh = VT + (size_t)bh * HEAD_DIM * SEQ;

    // Q fragments (B operand): n = l15 = q, k = kt*32+quad*8
    bf16x8 qfh[2], qfl[2];
#pragma unroll
    for (int kt = 0; kt < 2; ++kt) {
        size_t off = (size_t)(qt * 64 + wv * 16 + l15) * HEAD_DIM + kt * 32 + quad * 8;
        qfh[kt] = ld8(Qbh_h + off);
        qfl[kt] = ld8(Qbh_l + off);
    }

    // staging pointers (wave covers tile rows [wv*16, wv*16+16))
    const int rr = lane >> 3;
    const int ss = lane & 7;
    const int cc = ss ^ rr;                // XOR chunk swizzle on global source
    const int row0 = wv * 16 + rr;
    const u16* kh0 = Kh_h + bh_off + (size_t)row0 * HEAD_DIM + cc * 8;
    const u16* kl0 = Kh_l + bh_off + (size_t)row0 * HEAD_DIM + cc * 8;
    const u16* v0  = Vbh + (size_t)row0 * SEQ + cc * 8;
    u16* ldsK0h = &Ksh[(wv * 16) * 64];
    u16* ldsK1h = &Ksh[(wv * 16 + 8) * 64];
    u16* ldsK0l = &Ksl[(wv * 16) * 64];
    u16* ldsK1l = &Ksl[(wv * 16 + 8) * 64];
    u16* ldsV0  = &Vs[(wv * 16) * 64];
    u16* ldsV1  = &Vs[(wv * 16 + 8) * 64];

    f32x4 acc_o[4];                        // Oᵀ[d][q]: col q=l15, row d=ni*16+quad*4+r
    float m_i = -3.0e38f, l_i = 0.f;       // per lane = per q column
#pragma unroll
    for (int ni = 0; ni < 4; ++ni) acc_o[ni] = (f32x4){0.f, 0.f, 0.f, 0.f};

    for (int j = 0; j < SEQ / 64; ++j) {
        __syncthreads();
        gl_lds16(kh0 + (size_t)j * 64 * HEAD_DIM,                ldsK0h);
        gl_lds16(kh0 + (size_t)j * 64 * HEAD_DIM + 8 * HEAD_DIM, ldsK1h);
        gl_lds16(kl0 + (size_t)j * 64 * HEAD_DIM,                ldsK0l);
        gl_lds16(kl0 + (size_t)j * 64 * HEAD_DIM + 8 * HEAD_DIM, ldsK1l);
        gl_lds16(v0 + j * 64,                                    ldsV0);
        gl_lds16(v0 + j * 64 + (size_t)8 * SEQ,                  ldsV1);
        __syncthreads();

        // --- Sᵀ = K·Qᵀ (64 keys x 16 q per wave), split precision ---
        f32x4 acc_s[4];   // Sᵀ[key][q]: col q=l15, row key=ni*16+quad*4+r
#pragma unroll
        for (int ni = 0; ni < 4; ++ni) acc_s[ni] = (f32x4){0.f, 0.f, 0.f, 0.f};
#pragma unroll
        for (int kt = 0; kt < 2; ++kt) {
            bf16x8 kfh[4], kfl[4];
#pragma unroll
            for (int ni = 0; ni < 4; ++ni) {
                int slot = (kt * 4 + quad) ^ (l15 & 7);
                kfh[ni] = ld8(&Ksh[(ni * 16 + l15) * 64 + slot * 8]);
                kfl[ni] = ld8(&Ksl[(ni * 16 + l15) * 64 + slot * 8]);
            }
#pragma unroll
            for (int ni = 0; ni < 4; ++ni) {
                acc_s[ni] = __builtin_amdgcn_mfma_f32_16x16x32_bf16(
                    kfh[ni], qfh[kt], acc_s[ni], 0, 0, 0);
                acc_s[ni] = __builtin_amdgcn_mfma_f32_16x16x32_bf16(
                    kfh[ni], qfl[kt], acc_s[ni], 0, 0, 0);
                acc_s[ni] = __builtin_amdgcn_mfma_f32_16x16x32_bf16(
                    kfl[ni], qfh[kt], acc_s[ni], 0, 0, 0);
            }
        }

        // --- online softmax: lane owns 16 scores of its q column ---
        float mx = acc_s[0][0];
#pragma unroll
        for (int ni = 0; ni < 4; ++ni)
#pragma unroll
            for (int r = 0; r < 4; ++r) mx = fmaxf(mx, acc_s[ni][r]);
        mx = fmaxf(mx, __shfl_xor(mx, 16, 64));
        mx = fmaxf(mx, __shfl_xor(mx, 32, 64));
        float mnew = fmaxf(m_i, mx);
        float alpha = __expf(m_i - mnew);
        float sum = 0.f;
        const int psBase = (wv * 16 + l15) * 72;   // Pᵀ -> Ps[q][key], wave-private rows
#pragma unroll
        for (int ni = 0; ni < 4; ++ni) {
            ushort4 pq;
            u16* pp = (u16*)&pq;
#pragma unroll
            for (int r = 0; r < 4; ++r) {
                float p = __expf(acc_s[ni][r] - mnew);
                uint32_t ub = __builtin_bit_cast(uint32_t, p) & 0xffff0000u;
                sum += __builtin_bit_cast(float, ub);   // l consistent with stored P
                pp[r] = (u16)(ub >> 16);
            }
            *reinterpret_cast<ushort4*>(&Ps[psBase + ni * 16 + quad * 4]) = pq;
        }
        sum += __shfl_xor(sum, 16, 64);
        sum += __shfl_xor(sum, 32, 64);
        m_i = mnew;
        l_i = l_i * alpha + sum;
#pragma unroll
        for (int ni = 0; ni < 4; ++ni) acc_o[ni] *= alpha;
        // no barrier: wave reads back only its own Ps rows

        // --- Oᵀ += Vᵀ·Pᵀ ---
#pragma unroll
        for (int kt = 0; kt < 2; ++kt) {
            bf16x8 pf = ld8(&Ps[psBase + kt * 32 + quad * 8]);
            bf16x8 vf[4];
#pragma unroll
            for (int ni = 0; ni < 4; ++ni) {
                int slot = (kt * 4 + quad) ^ (l15 & 7);
                vf[ni] = ld8(&Vs[(ni * 16 + l15) * 64 + slot * 8]);
            }
#pragma unroll
            for (int ni = 0; ni < 4; ++ni)
                acc_o[ni] = __builtin_amdgcn_mfma_f32_16x16x32_bf16(
                    vf[ni], pf, acc_o[ni], 0, 0, 0);
        }
    }

    // --- epilogue: scale by 1/l, transpose Oᵀ through LDS, coalesced bf16 stores ---
    const float inv = 1.0f / l_i;
    const int psBase = (wv * 16 + l15) * 72;
#pragma unroll
    for (int ni = 0; ni < 4; ++ni) {
        ushort4 oq;
        u16* op = (u16*)&oq;
#pragma unroll
        for (int r = 0; r < 4; ++r) op[r] = f2bf(acc_o[ni][r] * inv);
        *reinterpret_cast<ushort4*>(&Ps[psBase + ni * 16 + quad * 4]) = oq;
    }
    const int b = bh >> 4, h = bh & 15;
    const int qrow = qt * 64 + wv * 16 + l15;      // this lane stores row q=l15
    bf16x8 o0 = ld8(&Ps[psBase + quad * 16]);
    bf16x8 o1 = ld8(&Ps[psBase + quad * 16 + 8]);
    size_t outb = ((size_t)(b * SEQ + qrow)) * D_MODEL + h * 64 + quad * 16;
    *reinterpret_cast<uint4*>(&AO[outb])     = __builtin_bit_cast(uint4, o0);
    *reinterpret_cast<uint4*>(&AO[outb + 8]) = __builtin_bit_cast(uint4, o1);
}

// ---------------- host ----------------
extern "C" void kernel_launch(void* const* d_in, const int* in_sizes, int n_in,
                              void* d_out, int out_size, void* d_ws, size_t ws_size,
                              hipStream_t stream) {
    const float* xq  = (const float*)d_in[0];
    const float* xc  = (const float*)d_in[1];
    const float* Wq  = (const float*)d_in[2];
    const float* Wkv = (const float*)d_in[3];
    const float* Wp  = (const float*)d_in[4];
    const float* bp  = (const float*)d_in[5];
    const float* lng = (const float*)d_in[6];
    const float* lnb = (const float*)d_in[7];
    float* out = (float*)d_out;

    char* ws = (char*)d_ws;
    const size_t MB = 1 << 20;
    u16* xq16   = (u16*)(ws + 0 * MB);    // 8 MB (fp16)
    u16* xc16   = (u16*)(ws + 8 * MB);    // 8 MB (fp16)
    u16* WqT16  = (u16*)(ws + 16 * MB);   // 2 MB (fp16)
    u16* WkvT16 = (u16*)(ws + 18 * MB);   // 4 MB (fp16)
    u16* WpT    = (u16*)(ws + 22 * MB);   // 2 MB (bf16)
    u16* Qh_h   = (u16*)(ws + 24 * MB);   // 8 MB
    u16* Qh_l   = (u16*)(ws + 32 * MB);   // 8 MB
    u16* Kh_h   = (u16*)(ws + 40 * MB);   // 8 MB
    u16* Kh_l   = (u16*)(ws + 48 * MB);   // 8 MB
    u16* VT     = (u16*)(ws + 56 * MB);   // 8 MB
    u16* AO     = xq16;   // alias: xq16 dead after k_proj_f16

    k_cast_f16<<<8192, 256, 0, stream>>>(xq, xc, xq16, xc16, 1048576);
    k_transpose_f16<<<dim3(32, 32), 256, 0, stream>>>(Wq, WqT16, 1024, 1024);
    k_transpose_f16<<<dim3(64, 32), 256, 0, stream>>>(Wkv, WkvT16, 1024, 2048);
    k_transpose_bf16<<<dim3(32, 32), 256, 0, stream>>>(Wp, WpT, 1024, 1024);

    k_proj_f16<<<dim3(24, 32), 256, 0, stream>>>(xq16, xc16, WqT16, WkvT16,
                                                 lng, lnb, Qh_h, Qh_l, Kh_h, Kh_l, VT);
    k_attn<<<1024, 256, 0, stream>>>(Qh_h, Qh_l, Kh_h, Kh_l, VT, AO);
    k_gemm_out<<<dim3(8, 32), 256, 0, stream>>>(AO, WpT, bp, out);
}

// Round 9
// 274.673 us; speedup vs baseline: 1.6362x; 1.0106x over previous
//
#include <hip/hip_runtime.h>
#include <stdint.h>

#define NUM_HEADS 16
#define HEAD_DIM 64
#define D_MODEL 1024
#define SEQ 2048
#define BATCH 2

typedef unsigned short u16;
typedef __bf16 bf16x8 __attribute__((ext_vector_type(8)));
typedef _Float16 f16x8 __attribute__((ext_vector_type(8)));
typedef float f32x4 __attribute__((ext_vector_type(4)));

__device__ __forceinline__ u16 f2bf(float f) {
    union { float f; uint32_t u; } v; v.f = f;
    uint32_t u = v.u;
    u += 0x7FFFu + ((u >> 16) & 1u);   // RNE
    return (u16)(u >> 16);
}
__device__ __forceinline__ float bf2f(u16 h) {
    union { uint32_t u; float f; } v; v.u = (uint32_t)h << 16; return v.f;
}
__device__ __forceinline__ u16 f2h(float f) {
    _Float16 h = (_Float16)f;
    return __builtin_bit_cast(u16, h);
}
// pack two f32 -> two f16 (RTZ) as a uint32
__device__ __forceinline__ uint32_t pkrtz(float a, float b) {
    return __builtin_bit_cast(uint32_t, __builtin_amdgcn_cvt_pkrtz(a, b));
}

__device__ __forceinline__ bf16x8 ld8(const u16* p) {
    return *reinterpret_cast<const bf16x8*>(p);
}
__device__ __forceinline__ f16x8 ld8h(const u16* p) {
    return *reinterpret_cast<const f16x8*>(p);
}

__device__ __forceinline__ void gl_lds16(const void* g, void* l) {
    __builtin_amdgcn_global_load_lds(
        (const __attribute__((address_space(1))) void*)g,
        (__attribute__((address_space(3))) void*)l,
        16, 0, 0);
}

// ---- DPP 16-lane sum (VALU pipe) ----
template <int CTRL>
__device__ __forceinline__ float dpp_mov(float x) {
    return __builtin_bit_cast(float,
        __builtin_amdgcn_update_dpp(0, __builtin_bit_cast(int, x), CTRL, 0xf, 0xf, true));
}
__device__ __forceinline__ float rowsum16(float x) {
    x += dpp_mov<0x121>(x);
    x += dpp_mov<0x122>(x);
    x += dpp_mov<0x124>(x);
    x += dpp_mov<0x128>(x);
    return x;
}

// ---------------- fused prep: cast xq,xc -> fp16 + transpose 3 weights -> fp16 ----------------
// blocks [0,8192): casts; [8192,9216): WqT; [9216,11264): WkvT; [11264,12288): WpT
__global__ __launch_bounds__(256) void k_prep(const float* __restrict__ xq,
                                              const float* __restrict__ xc,
                                              const float* __restrict__ Wq,
                                              const float* __restrict__ Wkv,
                                              const float* __restrict__ Wp,
                                              u16* __restrict__ xq16,
                                              u16* __restrict__ xc16,
                                              u16* __restrict__ WqT16,
                                              u16* __restrict__ WkvT16,
                                              u16* __restrict__ WpT16) {
    __shared__ float tile[32][33];
    const int t = blockIdx.x;
    if (t < 8192) {
        int i = t * 256 + threadIdx.x;
        const float* src; u16* dst; int j;
        if (i < 1048576) { src = xq; dst = xq16; j = i; }
        else             { src = xc; dst = xc16; j = i - 1048576; }
        float4 v = reinterpret_cast<const float4*>(src)[j];
        ushort4 o;
        o.x = f2h(v.x); o.y = f2h(v.y); o.z = f2h(v.z); o.w = f2h(v.w);
        reinterpret_cast<ushort4*>(dst)[j] = o;
        return;
    }
    const float* W; u16* WT; int N, bi;
    if (t < 9216)       { W = Wq;  WT = WqT16;  N = 1024; bi = t - 8192; }
    else if (t < 11264) { W = Wkv; WT = WkvT16; N = 2048; bi = t - 9216; }
    else                { W = Wp;  WT = WpT16;  N = 1024; bi = t - 11264; }
    const int K = 1024;
    const int nb = N / 32;
    const int bn = (bi % nb) * 32, bk = (bi / nb) * 32;
    const int tx = threadIdx.x & 31;
    const int ty = threadIdx.x >> 5;
#pragma unroll
    for (int i = 0; i < 32; i += 8)
        tile[ty + i][tx] = W[(size_t)(bk + ty + i) * N + bn + tx];
    __syncthreads();
#pragma unroll
    for (int i = 0; i < 32; i += 8)
        WT[(size_t)(bn + ty + i) * K + bk + tx] = f2h(tile[tx][ty + i]);
}

// ---------------- fp16 GEMM mainloop (m97 structure) ----------------
__device__ __forceinline__ void gemm_mainloop_f16(const u16* __restrict__ A,
                                                  const u16* __restrict__ Bt,
                                                  u16* As, u16* Bs,
                                                  int tileM, int tileN, int K,
                                                  f32x4 acc[4][4]) {
    const int tid = threadIdx.x;
    const int lane = tid & 63;
    const int wv = tid >> 6;
    const int wm = wv >> 1, wn = wv & 1;
    const int quad = lane >> 4, l15 = lane & 15;

    const int c0 = tid, c1 = tid + 256;
    const u16* Ap0 = A + (size_t)(tileM + (c0 >> 2)) * K + (c0 & 3) * 8;
    const u16* Ap1 = A + (size_t)(tileM + (c1 >> 2)) * K + (c1 & 3) * 8;
    const u16* Bp0 = Bt + (size_t)(tileN + (c0 >> 2)) * K + (c0 & 3) * 8;
    const u16* Bp1 = Bt + (size_t)(tileN + (c1 >> 2)) * K + (c1 & 3) * 8;

    for (int k0 = 0; k0 < K; k0 += 32) {
        __syncthreads();
        gl_lds16(Ap0 + k0, &As[c0 * 8]);
        gl_lds16(Ap1 + k0, &As[c1 * 8]);
        gl_lds16(Bp0 + k0, &Bs[c0 * 8]);
        gl_lds16(Bp1 + k0, &Bs[c1 * 8]);
        __syncthreads();
        f16x8 af[4], bfr[4];
#pragma unroll
        for (int mi = 0; mi < 4; ++mi)
            af[mi] = ld8h(&As[(wm * 64 + mi * 16 + l15) * 32 + quad * 8]);
#pragma unroll
        for (int ni = 0; ni < 4; ++ni)
            bfr[ni] = ld8h(&Bs[(wn * 64 + ni * 16 + l15) * 32 + quad * 8]);
#pragma unroll
        for (int mi = 0; mi < 4; ++mi)
#pragma unroll
            for (int ni = 0; ni < 4; ++ni)
                acc[mi][ni] = __builtin_amdgcn_mfma_f32_16x16x32_f16(
                    af[mi], bfr[ni], acc[mi][ni], 0, 0, 0);
    }
}

#define ACC_INIT()                                                   \
    f32x4 acc[4][4];                                                 \
    _Pragma("unroll") for (int i = 0; i < 4; ++i)                    \
        _Pragma("unroll") for (int j = 0; j < 4; ++j)                \
            acc[i][j] = (f32x4){0.f, 0.f, 0.f, 0.f};

// ---------------- fused QKV projection (fp16 GEMM): Q/K -> LN + split-bf16, V -> fp16 VT ----------------
__global__ __launch_bounds__(256, 2) void k_proj_f16(const u16* __restrict__ xq16,
                                                     const u16* __restrict__ xc16,
                                                     const u16* __restrict__ WqT16,
                                                     const u16* __restrict__ WkvT16,
                                                     const float* __restrict__ lng,
                                                     const float* __restrict__ lnb,
                                                     u16* __restrict__ Qh_h,
                                                     u16* __restrict__ Qh_l,
                                                     u16* __restrict__ Kh_h,
                                                     u16* __restrict__ Kh_l,
                                                     u16* __restrict__ VT) {
    __shared__ __align__(16) u16 As[128 * 32];
    __shared__ __align__(16) u16 Bs[128 * 32];
    const int bx = blockIdx.x;
    const int tileM = blockIdx.y * 128;
    const int tid = threadIdx.x;
    const int lane = tid & 63;
    const int wv = tid >> 6;
    const int wm = wv >> 1, wn = wv & 1;
    const int quad = lane >> 4, l15 = lane & 15;
    ACC_INIT();

    if (bx < 16) {   // Q or K: fp16 GEMM + LayerNorm + split-bf16 store
        const bool isQ = bx < 8;
        const int tileN = (bx & 7) * 128;
        const u16* Axx = isQ ? xq16 : xc16;
        const u16* Bt  = isQ ? WqT16 : WkvT16;
        u16* Dh = isQ ? Qh_h : Kh_h;
        u16* Dl = isQ ? Qh_l : Kh_l;
        const float scl = isQ ? 8.0f : 1.0f;

        gemm_mainloop_f16(Axx, Bt, As, Bs, tileM, tileN, D_MODEL, acc);

        float gv[4], bv[4];
#pragma unroll
        for (int ni = 0; ni < 4; ++ni) { gv[ni] = lng[ni * 16 + l15]; bv[ni] = lnb[ni * 16 + l15]; }

#pragma unroll
        for (int mi = 0; mi < 4; ++mi) {
#pragma unroll
            for (int r = 0; r < 4; ++r) {
                float sum = 0.f, sq = 0.f;
#pragma unroll
                for (int ni = 0; ni < 4; ++ni) { float x = acc[mi][ni][r]; sum += x; sq += x * x; }
                sum = rowsum16(sum);
                sq  = rowsum16(sq);
                float mu = sum * (1.f / 64.f);
                float var = sq * (1.f / 64.f) - mu * mu;
                float rs = rsqrtf(var + 1e-5f);
                int m = tileM + wm * 64 + mi * 16 + quad * 4 + r;
                int bb = m >> 11, n = m & (SEQ - 1);
#pragma unroll
                for (int ni = 0; ni < 4; ++ni) {
                    int colg = tileN + wn * 64 + ni * 16 + l15;
                    int h = colg >> 6;
                    float y = ((acc[mi][ni][r] - mu) * rs * gv[ni] + bv[ni]) * scl;
                    size_t idx = (((size_t)bb * NUM_HEADS + h) * SEQ + n) * HEAD_DIM + (colg & 63);
                    u16 yh = f2bf(y);
                    Dh[idx] = yh;
                    Dl[idx] = f2bf(y - bf2f(yh));
                }
            }
        }
    } else {         // V: fp16 GEMM, store fp16 transposed (d-major)
        const int tileN = D_MODEL + (bx - 16) * 128;
        gemm_mainloop_f16(xc16, WkvT16, As, Bs, tileM, tileN, D_MODEL, acc);
#pragma unroll
        for (int mi = 0; mi < 4; ++mi) {
            int m0 = tileM + wm * 64 + mi * 16 + quad * 4;
            int bb = m0 >> 11, n0 = m0 & (SEQ - 1);
#pragma unroll
            for (int ni = 0; ni < 4; ++ni) {
                int colg = tileN + wn * 64 + ni * 16 + l15 - D_MODEL;
                int h = colg >> 6, d = colg & 63;
                ushort4 o;
                o.x = f2h(acc[mi][ni][0]);
                o.y = f2h(acc[mi][ni][1]);
                o.z = f2h(acc[mi][ni][2]);
                o.w = f2h(acc[mi][ni][3]);
                *reinterpret_cast<ushort4*>(
                    &VT[(((size_t)bb * NUM_HEADS + h) * HEAD_DIM + d) * SEQ + n0]) = o;
            }
        }
    }
}

// ---------------- output projection + bias -> out fp32 (fp16 GEMM) ----------------
__global__ __launch_bounds__(256, 2) void k_gemm_out(const u16* __restrict__ A,
                                                     const u16* __restrict__ Bt,
                                                     const float* __restrict__ bp,
                                                     float* __restrict__ out) {
    __shared__ __align__(16) u16 As[128 * 32];
    __shared__ __align__(16) u16 Bs[128 * 32];
    const int tileM = blockIdx.y * 128, tileN = blockIdx.x * 128;
    const int tid = threadIdx.x;
    const int lane = tid & 63;
    const int wv = tid >> 6;
    const int wm = wv >> 1, wn = wv & 1;
    const int quad = lane >> 4, l15 = lane & 15;
    ACC_INIT();
    gemm_mainloop_f16(A, Bt, As, Bs, tileM, tileN, D_MODEL, acc);

    float bpv[4];
#pragma unroll
    for (int ni = 0; ni < 4; ++ni) bpv[ni] = bp[tileN + wn * 64 + ni * 16 + l15];
#pragma unroll
    for (int mi = 0; mi < 4; ++mi) {
#pragma unroll
        for (int r = 0; r < 4; ++r) {
            int m = tileM + wm * 64 + mi * 16 + quad * 4 + r;
#pragma unroll
            for (int ni = 0; ni < 4; ++ni) {
                int colg = tileN + wn * 64 + ni * 16 + l15;
                out[(size_t)m * D_MODEL + colg] = acc[mi][ni][r] + bpv[ni];
            }
        }
    }
}

// ---------------- flash attention v5: Sᵀ layout + double-buffered global_load_lds ----------------
// One barrier per iter: stage(0); loop { barrier; stage(j+1); compute(j); }.
// The compiler's vmcnt(0)-drain before s_barrier is the correctness mechanism:
// loads for j+1 (issued after barrier(j)) get all of compute(j) to land and are
// drained at barrier(j+1). No register staging (global_load_lds) -> no spill.
// P/V/AO in fp16 (cvt_pkrtz packing); QKᵀ stays split-bf16 (3 MFMA, exact hh).
__global__ __launch_bounds__(256) void k_attn(const u16* __restrict__ Qh_h,
                                              const u16* __restrict__ Qh_l,
                                              const u16* __restrict__ Kh_h,
                                              const u16* __restrict__ Kh_l,
                                              const u16* __restrict__ VT,
                                              u16* __restrict__ AO) {
    __shared__ __align__(16) u16 Ksh[2 * 64 * 64];
    __shared__ __align__(16) u16 Ksl[2 * 64 * 64];
    __shared__ __align__(16) u16 Vs[2 * 64 * 64];
    __shared__ __align__(16) u16 Ps[64 * 72];

    const int tid = threadIdx.x;
    const int lane = tid & 63;
    const int wv = tid >> 6;               // wave owns q cols [wv*16, wv*16+16)
    const int quad = lane >> 4, l15 = lane & 15;
    const int id = blockIdx.x;             // 0..1023
    const int bh = (id & 7) | (((id >> 8) & 3) << 3);  // bh&7 == XCD id
    const int qt = (id >> 3) & 31;

    const size_t bh_off = (size_t)bh * SEQ * HEAD_DIM;
    const u16* Qbh_h = Qh_h + bh_off;
    const u16* Qbh_l = Qh_l + bh_off;
    const u16* Vbh = VT + (size_t)bh * HEAD_DIM * SEQ;

    // Q fragments (B operand): n = l15 = q, k = kt*32+quad*8
    bf16x8 qfh[2], qfl[2];
#pragma unroll
    for (int kt = 0; kt < 2; ++kt) {
        size_t off = (size_t)(qt * 64 + wv * 16 + l15) * HEAD_DIM + kt * 32 + quad * 8;
        qfh[kt] = ld8(Qbh_h + off);
        qfl[kt] = ld8(Qbh_l + off);
    }

    // staging pointers (wave covers tile rows [wv*16, wv*16+16))
    const int rr = lane >> 3;
    const int ss = lane & 7;
    const int cc = ss ^ rr;                // XOR chunk swizzle on global source
    const int row0 = wv * 16 + rr;
    const u16* kh0 = Kh_h + bh_off + (size_t)row0 * HEAD_DIM + cc * 8;
    const u16* kl0 = Kh_l + bh_off + (size_t)row0 * HEAD_DIM + cc * 8;
    const u16* v0  = Vbh + (size_t)row0 * SEQ + cc * 8;
    const int ldsW = (wv * 16) * 64;       // wave's row base within a buffer

    f32x4 acc_o[4];                        // Oᵀ[d][q]: col q=l15, row d=ni*16+quad*4+r
    float m_i = -3.0e38f, l_i = 0.f;
#pragma unroll
    for (int ni = 0; ni < 4; ++ni) acc_o[ni] = (f32x4){0.f, 0.f, 0.f, 0.f};

    // prologue: stage tile 0 into buffer 0
    {
        gl_lds16(kh0,                 &Ksh[ldsW]);
        gl_lds16(kh0 + 8 * HEAD_DIM,  &Ksh[ldsW + 8 * 64]);
        gl_lds16(kl0,                 &Ksl[ldsW]);
        gl_lds16(kl0 + 8 * HEAD_DIM,  &Ksl[ldsW + 8 * 64]);
        gl_lds16(v0,                  &Vs[ldsW]);
        gl_lds16(v0 + 8 * SEQ,        &Vs[ldsW + 8 * 64]);
    }

    for (int j = 0; j < SEQ / 64; ++j) {
        __syncthreads();   // drains vmcnt -> buf[j&1] ready; all waves done with buf[(j+1)&1]
        if (j + 1 < SEQ / 64) {
            const int nb = (j + 1) & 1;
            const size_t ko = (size_t)(j + 1) * 64 * HEAD_DIM;
            const int vo = (j + 1) * 64;
            gl_lds16(kh0 + ko,                 &Ksh[nb * 4096 + ldsW]);
            gl_lds16(kh0 + ko + 8 * HEAD_DIM,  &Ksh[nb * 4096 + ldsW + 8 * 64]);
            gl_lds16(kl0 + ko,                 &Ksl[nb * 4096 + ldsW]);
            gl_lds16(kl0 + ko + 8 * HEAD_DIM,  &Ksl[nb * 4096 + ldsW + 8 * 64]);
            gl_lds16(v0 + vo,                  &Vs[nb * 4096 + ldsW]);
            gl_lds16(v0 + vo + 8 * SEQ,        &Vs[nb * 4096 + ldsW + 8 * 64]);
        }
        const int bb = (j & 1) * 4096;

        // --- Sᵀ = K·Qᵀ (64 keys x 16 q per wave), split precision ---
        f32x4 acc_s[4];   // Sᵀ[key][q]: col q=l15, row key=ni*16+quad*4+r
#pragma unroll
        for (int ni = 0; ni < 4; ++ni) acc_s[ni] = (f32x4){0.f, 0.f, 0.f, 0.f};
#pragma unroll
        for (int kt = 0; kt < 2; ++kt) {
            bf16x8 kfh[4], kfl[4];
#pragma unroll
            for (int ni = 0; ni < 4; ++ni) {
                int slot = (kt * 4 + quad) ^ (l15 & 7);
                kfh[ni] = ld8(&Ksh[bb + (ni * 16 + l15) * 64 + slot * 8]);
                kfl[ni] = ld8(&Ksl[bb + (ni * 16 + l15) * 64 + slot * 8]);
            }
#pragma unroll
            for (int ni = 0; ni < 4; ++ni) {
                acc_s[ni] = __builtin_amdgcn_mfma_f32_16x16x32_bf16(
                    kfh[ni], qfh[kt], acc_s[ni], 0, 0, 0);
                acc_s[ni] = __builtin_amdgcn_mfma_f32_16x16x32_bf16(
                    kfh[ni], qfl[kt], acc_s[ni], 0, 0, 0);
                acc_s[ni] = __builtin_amdgcn_mfma_f32_16x16x32_bf16(
                    kfl[ni], qfh[kt], acc_s[ni], 0, 0, 0);
            }
        }

        // --- online softmax: lane owns 16 scores of its q column ---
        float mx = acc_s[0][0];
#pragma unroll
        for (int ni = 0; ni < 4; ++ni)
#pragma unroll
            for (int r = 0; r < 4; ++r) mx = fmaxf(mx, acc_s[ni][r]);
        mx = fmaxf(mx, __shfl_xor(mx, 16, 64));
        mx = fmaxf(mx, __shfl_xor(mx, 32, 64));
        float mnew = fmaxf(m_i, mx);
        float alpha = __expf(m_i - mnew);
        float sum = 0.f;
        const int psBase = (wv * 16 + l15) * 72;   // Pᵀ rows are wave-private
#pragma unroll
        for (int ni = 0; ni < 4; ++ni) {
            float p0 = __expf(acc_s[ni][0] - mnew);
            float p1 = __expf(acc_s[ni][1] - mnew);
            float p2 = __expf(acc_s[ni][2] - mnew);
            float p3 = __expf(acc_s[ni][3] - mnew);
            sum += (p0 + p1) + (p2 + p3);
            uint2 u;
            u.x = pkrtz(p0, p1);
            u.y = pkrtz(p2, p3);
            *reinterpret_cast<uint2*>(&Ps[psBase + ni * 16 + quad * 4]) = u;
        }
        sum += __shfl_xor(sum, 16, 64);
        sum += __shfl_xor(sum, 32, 64);
        m_i = mnew;
        l_i = l_i * alpha + sum;
#pragma unroll
        for (int ni = 0; ni < 4; ++ni) acc_o[ni] *= alpha;
        // no barrier: wave reads back only its own Ps rows

        // --- Oᵀ += Vᵀ·Pᵀ (fp16) ---
#pragma unroll
        for (int kt = 0; kt < 2; ++kt) {
            f16x8 pf = ld8h(&Ps[psBase + kt * 32 + quad * 8]);
            f16x8 vf[4];
#pragma unroll
            for (int ni = 0; ni < 4; ++ni) {
                int slot = (kt * 4 + quad) ^ (l15 & 7);
                vf[ni] = ld8h(&Vs[bb + (ni * 16 + l15) * 64 + slot * 8]);
            }
#pragma unroll
            for (int ni = 0; ni < 4; ++ni)
                acc_o[ni] = __builtin_amdgcn_mfma_f32_16x16x32_f16(
                    vf[ni], pf, acc_o[ni], 0, 0, 0);
        }
    }

    // --- epilogue: scale 1/l, transpose Oᵀ via Ps (fp16), coalesced stores ---
    const float inv = 1.0f / l_i;
    const int psBase = (wv * 16 + l15) * 72;
#pragma unroll
    for (int ni = 0; ni < 4; ++ni) {
        uint2 u;
        u.x = pkrtz(acc_o[ni][0] * inv, acc_o[ni][1] * inv);
        u.y = pkrtz(acc_o[ni][2] * inv, acc_o[ni][3] * inv);
        *reinterpret_cast<uint2*>(&Ps[psBase + ni * 16 + quad * 4]) = u;
    }
    const int b = bh >> 4, h = bh & 15;
    const int qrow = qt * 64 + wv * 16 + l15;      // this lane stores row q=l15
    uint4 o0 = *reinterpret_cast<const uint4*>(&Ps[psBase + quad * 16]);
    uint4 o1 = *reinterpret_cast<const uint4*>(&Ps[psBase + quad * 16 + 8]);
    size_t outb = ((size_t)(b * SEQ + qrow)) * D_MODEL + h * 64 + quad * 16;
    *reinterpret_cast<uint4*>(&AO[outb])     = o0;
    *reinterpret_cast<uint4*>(&AO[outb + 8]) = o1;
}

// ---------------- host ----------------
extern "C" void kernel_launch(void* const* d_in, const int* in_sizes, int n_in,
                              void* d_out, int out_size, void* d_ws, size_t ws_size,
                              hipStream_t stream) {
    const float* xq  = (const float*)d_in[0];
    const float* xc  = (const float*)d_in[1];
    const float* Wq  = (const float*)d_in[2];
    const float* Wkv = (const float*)d_in[3];
    const float* Wp  = (const float*)d_in[4];
    const float* bp  = (const float*)d_in[5];
    const float* lng = (const float*)d_in[6];
    const float* lnb = (const float*)d_in[7];
    float* out = (float*)d_out;

    char* ws = (char*)d_ws;
    const size_t MB = 1 << 20;
    u16* xq16   = (u16*)(ws + 0 * MB);    // 8 MB (fp16)
    u16* xc16   = (u16*)(ws + 8 * MB);    // 8 MB (fp16)
    u16* WqT16  = (u16*)(ws + 16 * MB);   // 2 MB (fp16)
    u16* WkvT16 = (u16*)(ws + 18 * MB);   // 4 MB (fp16)
    u16* WpT16  = (u16*)(ws + 22 * MB);   // 2 MB (fp16)
    u16* Qh_h   = (u16*)(ws + 24 * MB);   // 8 MB (bf16 hi)
    u16* Qh_l   = (u16*)(ws + 32 * MB);   // 8 MB (bf16 lo)
    u16* Kh_h   = (u16*)(ws + 40 * MB);   // 8 MB
    u16* Kh_l   = (u16*)(ws + 48 * MB);   // 8 MB
    u16* VT     = (u16*)(ws + 56 * MB);   // 8 MB (fp16)
    u16* AO     = xq16;   // alias: xq16 dead after k_proj_f16 (fp16)

    k_prep<<<12288, 256, 0, stream>>>(xq, xc, Wq, Wkv, Wp,
                                      xq16, xc16, WqT16, WkvT16, WpT16);
    k_proj_f16<<<dim3(24, 32), 256, 0, stream>>>(xq16, xc16, WqT16, WkvT16,
                                                 lng, lnb, Qh_h, Qh_l, Kh_h, Kh_l, VT);
    k_attn<<<1024, 256, 0, stream>>>(Qh_h, Qh_l, Kh_h, Kh_l, VT, AO);
    k_gemm_out<<<dim3(8, 32), 256, 0, stream>>>(AO, WpT16, bp, out);
}

// Round 10
// 262.181 us; speedup vs baseline: 1.7141x; 1.0476x over previous
//
#include <hip/hip_runtime.h>
#include <stdint.h>

#define NUM_HEADS 16
#define HEAD_DIM 64
#define D_MODEL 1024
#define SEQ 2048
#define BATCH 2

typedef unsigned short u16;
typedef _Float16 f16x8 __attribute__((ext_vector_type(8)));
typedef float f32x4 __attribute__((ext_vector_type(4)));

__device__ __forceinline__ u16 f2h(float f) {
    _Float16 h = (_Float16)f;
    return __builtin_bit_cast(u16, h);
}
__device__ __forceinline__ float h2f(u16 h) {
    return (float)__builtin_bit_cast(_Float16, h);
}
// pack two f32 -> two f16 (RTZ) as a uint32
__device__ __forceinline__ uint32_t pkrtz(float a, float b) {
    return __builtin_bit_cast(uint32_t, __builtin_amdgcn_cvt_pkrtz(a, b));
}

__device__ __forceinline__ f16x8 ld8h(const u16* p) {
    return *reinterpret_cast<const f16x8*>(p);
}

__device__ __forceinline__ void gl_lds16(const void* g, void* l) {
    __builtin_amdgcn_global_load_lds(
        (const __attribute__((address_space(1))) void*)g,
        (__attribute__((address_space(3))) void*)l,
        16, 0, 0);
}

// ---- DPP 16-lane sum (VALU pipe) ----
template <int CTRL>
__device__ __forceinline__ float dpp_mov(float x) {
    return __builtin_bit_cast(float,
        __builtin_amdgcn_update_dpp(0, __builtin_bit_cast(int, x), CTRL, 0xf, 0xf, true));
}
__device__ __forceinline__ float rowsum16(float x) {
    x += dpp_mov<0x121>(x);
    x += dpp_mov<0x122>(x);
    x += dpp_mov<0x124>(x);
    x += dpp_mov<0x128>(x);
    return x;
}

// ---------------- fused prep: cast xq,xc -> fp16 + transpose 3 weights -> fp16 ----------------
__global__ __launch_bounds__(256) void k_prep(const float* __restrict__ xq,
                                              const float* __restrict__ xc,
                                              const float* __restrict__ Wq,
                                              const float* __restrict__ Wkv,
                                              const float* __restrict__ Wp,
                                              u16* __restrict__ xq16,
                                              u16* __restrict__ xc16,
                                              u16* __restrict__ WqT16,
                                              u16* __restrict__ WkvT16,
                                              u16* __restrict__ WpT16) {
    __shared__ float tile[32][33];
    const int t = blockIdx.x;
    if (t < 8192) {
        int i = t * 256 + threadIdx.x;
        const float* src; u16* dst; int j;
        if (i < 1048576) { src = xq; dst = xq16; j = i; }
        else             { src = xc; dst = xc16; j = i - 1048576; }
        float4 v = reinterpret_cast<const float4*>(src)[j];
        ushort4 o;
        o.x = f2h(v.x); o.y = f2h(v.y); o.z = f2h(v.z); o.w = f2h(v.w);
        reinterpret_cast<ushort4*>(dst)[j] = o;
        return;
    }
    const float* W; u16* WT; int N, bi;
    if (t < 9216)       { W = Wq;  WT = WqT16;  N = 1024; bi = t - 8192; }
    else if (t < 11264) { W = Wkv; WT = WkvT16; N = 2048; bi = t - 9216; }
    else                { W = Wp;  WT = WpT16;  N = 1024; bi = t - 11264; }
    const int K = 1024;
    const int nb = N / 32;
    const int bn = (bi % nb) * 32, bk = (bi / nb) * 32;
    const int tx = threadIdx.x & 31;
    const int ty = threadIdx.x >> 5;
#pragma unroll
    for (int i = 0; i < 32; i += 8)
        tile[ty + i][tx] = W[(size_t)(bk + ty + i) * N + bn + tx];
    __syncthreads();
#pragma unroll
    for (int i = 0; i < 32; i += 8)
        WT[(size_t)(bn + ty + i) * K + bk + tx] = f2h(tile[tx][ty + i]);
}

// ---------------- fp16 GEMM mainloop (m97 structure) ----------------
__device__ __forceinline__ void gemm_mainloop_f16(const u16* __restrict__ A,
                                                  const u16* __restrict__ Bt,
                                                  u16* As, u16* Bs,
                                                  int tileM, int tileN, int K,
                                                  f32x4 acc[4][4]) {
    const int tid = threadIdx.x;
    const int lane = tid & 63;
    const int wv = tid >> 6;
    const int wm = wv >> 1, wn = wv & 1;
    const int quad = lane >> 4, l15 = lane & 15;

    const int c0 = tid, c1 = tid + 256;
    const u16* Ap0 = A + (size_t)(tileM + (c0 >> 2)) * K + (c0 & 3) * 8;
    const u16* Ap1 = A + (size_t)(tileM + (c1 >> 2)) * K + (c1 & 3) * 8;
    const u16* Bp0 = Bt + (size_t)(tileN + (c0 >> 2)) * K + (c0 & 3) * 8;
    const u16* Bp1 = Bt + (size_t)(tileN + (c1 >> 2)) * K + (c1 & 3) * 8;

    for (int k0 = 0; k0 < K; k0 += 32) {
        __syncthreads();
        gl_lds16(Ap0 + k0, &As[c0 * 8]);
        gl_lds16(Ap1 + k0, &As[c1 * 8]);
        gl_lds16(Bp0 + k0, &Bs[c0 * 8]);
        gl_lds16(Bp1 + k0, &Bs[c1 * 8]);
        __syncthreads();
        f16x8 af[4], bfr[4];
#pragma unroll
        for (int mi = 0; mi < 4; ++mi)
            af[mi] = ld8h(&As[(wm * 64 + mi * 16 + l15) * 32 + quad * 8]);
#pragma unroll
        for (int ni = 0; ni < 4; ++ni)
            bfr[ni] = ld8h(&Bs[(wn * 64 + ni * 16 + l15) * 32 + quad * 8]);
#pragma unroll
        for (int mi = 0; mi < 4; ++mi)
#pragma unroll
            for (int ni = 0; ni < 4; ++ni)
                acc[mi][ni] = __builtin_amdgcn_mfma_f32_16x16x32_f16(
                    af[mi], bfr[ni], acc[mi][ni], 0, 0, 0);
    }
}

#define ACC_INIT()                                                   \
    f32x4 acc[4][4];                                                 \
    _Pragma("unroll") for (int i = 0; i < 4; ++i)                    \
        _Pragma("unroll") for (int j = 0; j < 4; ++j)                \
            acc[i][j] = (f32x4){0.f, 0.f, 0.f, 0.f};

// ---------------- fused QKV projection: Q -> LN + split-fp16, K -> LN + fp16, V -> fp16 VT ----------------
__global__ __launch_bounds__(256, 2) void k_proj_f16(const u16* __restrict__ xq16,
                                                     const u16* __restrict__ xc16,
                                                     const u16* __restrict__ WqT16,
                                                     const u16* __restrict__ WkvT16,
                                                     const float* __restrict__ lng,
                                                     const float* __restrict__ lnb,
                                                     u16* __restrict__ Qh_h,
                                                     u16* __restrict__ Qh_l,
                                                     u16* __restrict__ Kh,
                                                     u16* __restrict__ VT) {
    __shared__ __align__(16) u16 As[128 * 32];
    __shared__ __align__(16) u16 Bs[128 * 32];
    const int bx = blockIdx.x;
    const int tileM = blockIdx.y * 128;
    const int tid = threadIdx.x;
    const int lane = tid & 63;
    const int wv = tid >> 6;
    const int wm = wv >> 1, wn = wv & 1;
    const int quad = lane >> 4, l15 = lane & 15;
    ACC_INIT();

    if (bx < 16) {   // Q or K: fp16 GEMM + LayerNorm
        const bool isQ = bx < 8;
        const int tileN = (bx & 7) * 128;
        const u16* Axx = isQ ? xq16 : xc16;
        const u16* Bt  = isQ ? WqT16 : WkvT16;
        const float scl = isQ ? 8.0f : 1.0f;

        gemm_mainloop_f16(Axx, Bt, As, Bs, tileM, tileN, D_MODEL, acc);

        float gv[4], bv[4];
#pragma unroll
        for (int ni = 0; ni < 4; ++ni) { gv[ni] = lng[ni * 16 + l15]; bv[ni] = lnb[ni * 16 + l15]; }

#pragma unroll
        for (int mi = 0; mi < 4; ++mi) {
#pragma unroll
            for (int r = 0; r < 4; ++r) {
                float sum = 0.f, sq = 0.f;
#pragma unroll
                for (int ni = 0; ni < 4; ++ni) { float x = acc[mi][ni][r]; sum += x; sq += x * x; }
                sum = rowsum16(sum);
                sq  = rowsum16(sq);
                float mu = sum * (1.f / 64.f);
                float var = sq * (1.f / 64.f) - mu * mu;
                float rs = rsqrtf(var + 1e-5f);
                int m = tileM + wm * 64 + mi * 16 + quad * 4 + r;
                int bb = m >> 11, n = m & (SEQ - 1);
#pragma unroll
                for (int ni = 0; ni < 4; ++ni) {
                    int colg = tileN + wn * 64 + ni * 16 + l15;
                    int h = colg >> 6;
                    float y = ((acc[mi][ni][r] - mu) * rs * gv[ni] + bv[ni]) * scl;
                    size_t idx = (((size_t)bb * NUM_HEADS + h) * SEQ + n) * HEAD_DIM + (colg & 63);
                    u16 yh = f2h(y);
                    if (isQ) {
                        Qh_h[idx] = yh;
                        Qh_l[idx] = f2h(y - h2f(yh));   // split-fp16: Q exact to ~2^-22
                    } else {
                        Kh[idx] = yh;                   // single fp16 (2^-11)
                    }
                }
            }
        }
    } else {         // V: fp16 GEMM, store fp16 transposed (d-major)
        const int tileN = D_MODEL + (bx - 16) * 128;
        gemm_mainloop_f16(xc16, WkvT16, As, Bs, tileM, tileN, D_MODEL, acc);
#pragma unroll
        for (int mi = 0; mi < 4; ++mi) {
            int m0 = tileM + wm * 64 + mi * 16 + quad * 4;
            int bb = m0 >> 11, n0 = m0 & (SEQ - 1);
#pragma unroll
            for (int ni = 0; ni < 4; ++ni) {
                int colg = tileN + wn * 64 + ni * 16 + l15 - D_MODEL;
                int h = colg >> 6, d = colg & 63;
                ushort4 o;
                o.x = f2h(acc[mi][ni][0]);
                o.y = f2h(acc[mi][ni][1]);
                o.z = f2h(acc[mi][ni][2]);
                o.w = f2h(acc[mi][ni][3]);
                *reinterpret_cast<ushort4*>(
                    &VT[(((size_t)bb * NUM_HEADS + h) * HEAD_DIM + d) * SEQ + n0]) = o;
            }
        }
    }
}

// ---------------- output projection + bias -> out fp32 (fp16 GEMM) ----------------
__global__ __launch_bounds__(256, 2) void k_gemm_out(const u16* __restrict__ A,
                                                     const u16* __restrict__ Bt,
                                                     const float* __restrict__ bp,
                                                     float* __restrict__ out) {
    __shared__ __align__(16) u16 As[128 * 32];
    __shared__ __align__(16) u16 Bs[128 * 32];
    const int tileM = blockIdx.y * 128, tileN = blockIdx.x * 128;
    const int tid = threadIdx.x;
    const int lane = tid & 63;
    const int wv = tid >> 6;
    const int wm = wv >> 1, wn = wv & 1;
    const int quad = lane >> 4, l15 = lane & 15;
    ACC_INIT();
    gemm_mainloop_f16(A, Bt, As, Bs, tileM, tileN, D_MODEL, acc);

    float bpv[4];
#pragma unroll
    for (int ni = 0; ni < 4; ++ni) bpv[ni] = bp[tileN + wn * 64 + ni * 16 + l15];
#pragma unroll
    for (int mi = 0; mi < 4; ++mi) {
#pragma unroll
        for (int r = 0; r < 4; ++r) {
            int m = tileM + wm * 64 + mi * 16 + quad * 4 + r;
#pragma unroll
            for (int ni = 0; ni < 4; ++ni) {
                int colg = tileN + wn * 64 + ni * 16 + l15;
                out[(size_t)m * D_MODEL + colg] = acc[mi][ni][r] + bpv[ni];
            }
        }
    }
}

// ---------------- flash attention v6: fp16 S (split-Q x single-K, 2 MFMAs),
// double-buffered global_load_lds, LDS = 40960 B exactly -> 4 blocks/CU.
// Ps: 64x64 stride, 16-col chunk index XORed with l15&3 -> writes at the
// wave64-b64 4-phase minimum, b128 reads at 8-phase minimum (free, m136).
__global__ __launch_bounds__(256) void k_attn(const u16* __restrict__ Qh_h,
                                              const u16* __restrict__ Qh_l,
                                              const u16* __restrict__ Kh,
                                              const u16* __restrict__ VT,
                                              u16* __restrict__ AO) {
    __shared__ __align__(16) u16 Ks[2 * 64 * 64];   // fp16, double-buffered
    __shared__ __align__(16) u16 Vs[2 * 64 * 64];   // fp16, double-buffered
    __shared__ __align__(16) u16 Ps[64 * 64];       // fp16, chunk-XOR swizzled

    const int tid = threadIdx.x;
    const int lane = tid & 63;
    const int wv = tid >> 6;               // wave owns q cols [wv*16, wv*16+16)
    const int quad = lane >> 4, l15 = lane & 15;
    const int sw = l15 & 3;                // Ps chunk XOR key
    const int id = blockIdx.x;             // 0..1023
    const int bh = (id & 7) | (((id >> 8) & 3) << 3);  // bh&7 == XCD id
    const int qt = (id >> 3) & 31;

    const size_t bh_off = (size_t)bh * SEQ * HEAD_DIM;
    const u16* Vbh = VT + (size_t)bh * HEAD_DIM * SEQ;

    // Q fragments (B operand), split fp16: n = l15 = q, k = kt*32+quad*8
    f16x8 qfh[2], qfl[2];
#pragma unroll
    for (int kt = 0; kt < 2; ++kt) {
        size_t off = bh_off + (size_t)(qt * 64 + wv * 16 + l15) * HEAD_DIM + kt * 32 + quad * 8;
        qfh[kt] = ld8h(Qh_h + off);
        qfl[kt] = ld8h(Qh_l + off);
    }

    // staging pointers (wave covers tile rows [wv*16, wv*16+16))
    const int rr = lane >> 3;
    const int ss = lane & 7;
    const int cc = ss ^ rr;                // XOR chunk swizzle on global source
    const int row0 = wv * 16 + rr;
    const u16* k0 = Kh + bh_off + (size_t)row0 * HEAD_DIM + cc * 8;
    const u16* v0 = Vbh + (size_t)row0 * SEQ + cc * 8;
    const int ldsW = (wv * 16) * 64;       // wave's row base within a buffer

    f32x4 acc_o[4];                        // Oᵀ[d][q]: col q=l15, row d=ni*16+quad*4+r
    float m_i = -3.0e38f, l_i = 0.f;
#pragma unroll
    for (int ni = 0; ni < 4; ++ni) acc_o[ni] = (f32x4){0.f, 0.f, 0.f, 0.f};

    // prologue: stage tile 0 into buffer 0
    gl_lds16(k0,                &Ks[ldsW]);
    gl_lds16(k0 + 8 * HEAD_DIM, &Ks[ldsW + 8 * 64]);
    gl_lds16(v0,                &Vs[ldsW]);
    gl_lds16(v0 + 8 * SEQ,      &Vs[ldsW + 8 * 64]);

    const int psRow = (wv * 16 + l15) * 64;    // Pᵀ rows are wave-private

    for (int j = 0; j < SEQ / 64; ++j) {
        __syncthreads();   // drains vmcnt -> buf[j&1] ready; all waves done with buf[(j+1)&1]
        if (j + 1 < SEQ / 64) {
            const int nb = (j + 1) & 1;
            const size_t ko = (size_t)(j + 1) * 64 * HEAD_DIM;
            const int vo = (j + 1) * 64;
            gl_lds16(k0 + ko,                &Ks[nb * 4096 + ldsW]);
            gl_lds16(k0 + ko + 8 * HEAD_DIM, &Ks[nb * 4096 + ldsW + 8 * 64]);
            gl_lds16(v0 + vo,                &Vs[nb * 4096 + ldsW]);
            gl_lds16(v0 + vo + 8 * SEQ,      &Vs[nb * 4096 + ldsW + 8 * 64]);
        }
        const int bb = (j & 1) * 4096;

        // --- Sᵀ = K·Qᵀ (64 keys x 16 q per wave): 2 fp16 MFMAs (kf·qh + kf·ql) ---
        f32x4 acc_s[4];   // Sᵀ[key][q]: col q=l15, row key=ni*16+quad*4+r
#pragma unroll
        for (int ni = 0; ni < 4; ++ni) acc_s[ni] = (f32x4){0.f, 0.f, 0.f, 0.f};
#pragma unroll
        for (int kt = 0; kt < 2; ++kt) {
            f16x8 kf[4];
#pragma unroll
            for (int ni = 0; ni < 4; ++ni) {
                int slot = (kt * 4 + quad) ^ (l15 & 7);
                kf[ni] = ld8h(&Ks[bb + (ni * 16 + l15) * 64 + slot * 8]);
            }
#pragma unroll
            for (int ni = 0; ni < 4; ++ni) {
                acc_s[ni] = __builtin_amdgcn_mfma_f32_16x16x32_f16(
                    kf[ni], qfh[kt], acc_s[ni], 0, 0, 0);
                acc_s[ni] = __builtin_amdgcn_mfma_f32_16x16x32_f16(
                    kf[ni], qfl[kt], acc_s[ni], 0, 0, 0);
            }
        }

        // --- online softmax: lane owns 16 scores of its q column ---
        float mx = acc_s[0][0];
#pragma unroll
        for (int ni = 0; ni < 4; ++ni)
#pragma unroll
            for (int r = 0; r < 4; ++r) mx = fmaxf(mx, acc_s[ni][r]);
        mx = fmaxf(mx, __shfl_xor(mx, 16, 64));
        mx = fmaxf(mx, __shfl_xor(mx, 32, 64));
        float mnew = fmaxf(m_i, mx);
        float alpha = __expf(m_i - mnew);
        float sum = 0.f;
#pragma unroll
        for (int ni = 0; ni < 4; ++ni) {
            float p0 = __expf(acc_s[ni][0] - mnew);
            float p1 = __expf(acc_s[ni][1] - mnew);
            float p2 = __expf(acc_s[ni][2] - mnew);
            float p3 = __expf(acc_s[ni][3] - mnew);
            sum += (p0 + p1) + (p2 + p3);
            uint2 u;
            u.x = pkrtz(p0, p1);
            u.y = pkrtz(p2, p3);
            *reinterpret_cast<uint2*>(&Ps[psRow + ((ni ^ sw) * 16) + quad * 4]) = u;
        }
        sum += __shfl_xor(sum, 16, 64);
        sum += __shfl_xor(sum, 32, 64);
        m_i = mnew;
        l_i = l_i * alpha + sum;
#pragma unroll
        for (int ni = 0; ni < 4; ++ni) acc_o[ni] *= alpha;
        // no barrier: wave reads back only its own Ps rows

        // --- Oᵀ += Vᵀ·Pᵀ (fp16) ---
#pragma unroll
        for (int kt = 0; kt < 2; ++kt) {
            int pchunk = (kt * 2 + (quad >> 1)) ^ sw;
            f16x8 pf = ld8h(&Ps[psRow + pchunk * 16 + (quad & 1) * 8]);
            f16x8 vf[4];
#pragma unroll
            for (int ni = 0; ni < 4; ++ni) {
                int slot = (kt * 4 + quad) ^ (l15 & 7);
                vf[ni] = ld8h(&Vs[bb + (ni * 16 + l15) * 64 + slot * 8]);
            }
#pragma unroll
            for (int ni = 0; ni < 4; ++ni)
                acc_o[ni] = __builtin_amdgcn_mfma_f32_16x16x32_f16(
                    vf[ni], pf, acc_o[ni], 0, 0, 0);
        }
    }

    // --- epilogue: scale 1/l, transpose Oᵀ via Ps (same swizzle), coalesced stores ---
    const float inv = 1.0f / l_i;
#pragma unroll
    for (int ni = 0; ni < 4; ++ni) {
        uint2 u;
        u.x = pkrtz(acc_o[ni][0] * inv, acc_o[ni][1] * inv);
        u.y = pkrtz(acc_o[ni][2] * inv, acc_o[ni][3] * inv);
        *reinterpret_cast<uint2*>(&Ps[psRow + ((ni ^ sw) * 16) + quad * 4]) = u;
    }
    const int b = bh >> 4, h = bh & 15;
    const int qrow = qt * 64 + wv * 16 + l15;      // this lane stores row q=l15
    const int echunk = quad ^ sw;
    uint4 o0 = *reinterpret_cast<const uint4*>(&Ps[psRow + echunk * 16]);
    uint4 o1 = *reinterpret_cast<const uint4*>(&Ps[psRow + echunk * 16 + 8]);
    size_t outb = ((size_t)(b * SEQ + qrow)) * D_MODEL + h * 64 + quad * 16;
    *reinterpret_cast<uint4*>(&AO[outb])     = o0;
    *reinterpret_cast<uint4*>(&AO[outb + 8]) = o1;
}

// ---------------- host ----------------
extern "C" void kernel_launch(void* const* d_in, const int* in_sizes, int n_in,
                              void* d_out, int out_size, void* d_ws, size_t ws_size,
                              hipStream_t stream) {
    const float* xq  = (const float*)d_in[0];
    const float* xc  = (const float*)d_in[1];
    const float* Wq  = (const float*)d_in[2];
    const float* Wkv = (const float*)d_in[3];
    const float* Wp  = (const float*)d_in[4];
    const float* bp  = (const float*)d_in[5];
    const float* lng = (const float*)d_in[6];
    const float* lnb = (const float*)d_in[7];
    float* out = (float*)d_out;

    char* ws = (char*)d_ws;
    const size_t MB = 1 << 20;
    u16* xq16   = (u16*)(ws + 0 * MB);    // 8 MB (fp16)
    u16* xc16   = (u16*)(ws + 8 * MB);    // 8 MB (fp16)
    u16* WqT16  = (u16*)(ws + 16 * MB);   // 2 MB (fp16)
    u16* WkvT16 = (u16*)(ws + 18 * MB);   // 4 MB (fp16)
    u16* WpT16  = (u16*)(ws + 22 * MB);   // 2 MB (fp16)
    u16* Qh_h   = (u16*)(ws + 24 * MB);   // 8 MB (fp16 hi)
    u16* Qh_l   = (u16*)(ws + 32 * MB);   // 8 MB (fp16 lo)
    u16* Kh     = (u16*)(ws + 40 * MB);   // 8 MB (fp16)
    u16* VT     = (u16*)(ws + 48 * MB);   // 8 MB (fp16)
    u16* AO     = xq16;   // alias: xq16 dead after k_proj_f16

    k_prep<<<12288, 256, 0, stream>>>(xq, xc, Wq, Wkv, Wp,
                                      xq16, xc16, WqT16, WkvT16, WpT16);
    k_proj_f16<<<dim3(24, 32), 256, 0, stream>>>(xq16, xc16, WqT16, WkvT16,
                                                 lng, lnb, Qh_h, Qh_l, Kh, VT);
    k_attn<<<1024, 256, 0, stream>>>(Qh_h, Qh_l, Kh, VT, AO);
    k_gemm_out<<<dim3(8, 32), 256, 0, stream>>>(AO, WpT16, bp, out);
}